// Round 5
// baseline (406.917 us; speedup 1.0000x reference)
//
#include <hip/hip_runtime.h>

#define DIN 128
#define BN_EPS 1e-5f

typedef __attribute__((ext_vector_type(8))) short bf16x8;
typedef __attribute__((ext_vector_type(8))) unsigned short us8;
typedef __attribute__((ext_vector_type(4))) float f32x4;

__device__ __forceinline__ ushort f2bf(float f) {
    unsigned u = __float_as_uint(f);
    u += 0x7fffu + ((u >> 16) & 1u);
    return (ushort)(u >> 16);
}
__device__ __forceinline__ float bf2f(ushort h) {
    return __uint_as_float(((unsigned)h) << 16);
}

// ======== barrier-free streaming GEMM: C[M,N](bf16) = A[M,K](bf16) @ BT[N,K]^T ========
// R2 structure (simple loop; no prefetch — R4 showed it neutral). NT = 16-col tiles per wave:
// NT=4 for K=128 (VGPR ~112); NT=2 for K=256 kernels to halve B-register footprint
// (bf[2][8]=64 VGPR vs 128) -> 3-4 waves/SIMD instead of 2 (occupancy was the R2-R4 limiter).
template<int KC, int NT, int STATS>
__global__ __launch_bounds__(256) void gemm_wreg(
    const ushort* __restrict__ A, const ushort* __restrict__ BT,
    ushort* __restrict__ C, int mStrips, int N, int K, int logNG,
    float* __restrict__ gsums, float* __restrict__ gsqs)
{
    int tid = threadIdx.x;
    int lane = tid & 63;
    int gw = blockIdx.x * 4 + (tid >> 6);
    int wg = gw & ((1 << logNG) - 1);
    int set = gw >> logNG;
    int totalSets = (gridDim.x * 4) >> logNG;
    int cl = lane & 15, q = lane >> 4;
    int colBase = wg * (16 * NT);

    bf16x8 bf[NT][KC];
    #pragma unroll
    for (int nt = 0; nt < NT; nt++) {
        const ushort* bp = BT + (long)(colBase + nt * 16 + cl) * K + q * 8;
        #pragma unroll
        for (int kc = 0; kc < KC; kc++)
            bf[nt][kc] = *(const bf16x8*)(bp + kc * 32);
    }

    float ssum[NT];
    float ssq[NT];
    #pragma unroll
    for (int nt = 0; nt < NT; nt++) { ssum[nt] = 0.f; ssq[nt] = 0.f; }

    for (int strip = set; strip < mStrips; strip += totalSets) {
        int rowBase = strip * 16;
        const ushort* ap = A + (long)(rowBase + cl) * K + q * 8;
        bf16x8 af[KC];
        #pragma unroll
        for (int kc = 0; kc < KC; kc++)
            af[kc] = *(const bf16x8*)(ap + kc * 32);
        f32x4 acc[NT] = {};
        #pragma unroll
        for (int kc = 0; kc < KC; kc++)
            #pragma unroll
            for (int nt = 0; nt < NT; nt++)
                acc[nt] = __builtin_amdgcn_mfma_f32_16x16x32_bf16(af[kc], bf[nt][kc], acc[nt], 0, 0, 0);
        #pragma unroll
        for (int nt = 0; nt < NT; nt++) {
            #pragma unroll
            for (int r = 0; r < 4; r++) {
                float v = acc[nt][r];
                long row = rowBase + q * 4 + r;
                C[row * N + colBase + nt * 16 + cl] = f2bf(v);
                if (STATS) { ssum[nt] += v; ssq[nt] += v * v; }
            }
        }
    }

    if (STATS) {
        #pragma unroll
        for (int nt = 0; nt < NT; nt++) {
            ssum[nt] += __shfl_xor(ssum[nt], 16, 64);
            ssum[nt] += __shfl_xor(ssum[nt], 32, 64);
            ssq[nt]  += __shfl_xor(ssq[nt], 16, 64);
            ssq[nt]  += __shfl_xor(ssq[nt], 32, 64);
        }
        if (q == 0) {
            #pragma unroll
            for (int nt = 0; nt < NT; nt++) {
                atomicAdd(&gsums[colBase + nt * 16 + cl], ssum[nt]);
                atomicAdd(&gsqs[colBase + nt * 16 + cl], ssq[nt]);
            }
        }
    }
}

// ======== fused setup: convert nodes -> bf16, transpose weights, zero stats + degi/cursor ========
__global__ __launch_bounds__(256) void setup_all(
    const float* __restrict__ nodes, ushort* __restrict__ Xbf, int nConv4, int nbConv,
    const float* __restrict__ W0, const float* __restrict__ W1,
    const float* __restrict__ W2, const float* __restrict__ W3,
    const float* __restrict__ W4, const float* __restrict__ W5,
    ushort* __restrict__ WT,
    int* __restrict__ zeroInts, int nZero4, int nbZero,
    float* __restrict__ stats)
{
    int b = blockIdx.x;
    int tid = threadIdx.x;
    if (b < nbConv) {
        int t = b * 256 + tid;
        if (t < nConv4) {
            float4 v = *(const float4*)&nodes[(long)t * 4];
            ushort4 o; o.x = f2bf(v.x); o.y = f2bf(v.y); o.z = f2bf(v.z); o.w = f2bf(v.w);
            *(ushort4*)&Xbf[(long)t * 4] = o;
        }
        return;
    }
    b -= nbConv;
    if (b < 768) {
        int seg = b >> 7;
        const float* W; int logK, dstBase, stride, kOff;
        switch (seg) {
            case 0: W = W0; logK = 7; dstBase = 0;      stride = 128; kOff = 0;   break;
            case 1: W = W1; logK = 8; dstBase = 32768;  stride = 256; kOff = 0;   break;
            case 2: W = W2; logK = 7; dstBase = 65536;  stride = 256; kOff = 0;   break;
            case 3: W = W3; logK = 7; dstBase = 65536;  stride = 256; kOff = 128; break;
            case 4: W = W4; logK = 8; dstBase = 131072; stride = 256; kOff = 0;   break;
            default:W = W5; logK = 8; dstBase = 163840; stride = 256; kOff = 0;   break;
        }
        int t = (b & 127) * 256 + tid;
        int N = 32768 >> logK;
        int k = t & ((1 << logK) - 1);
        int n = t >> logK;
        WT[(long)dstBase + (long)n * stride + kOff + k] = f2bf(W[(long)k * N + n]);
        return;
    }
    b -= 768;
    if (b < nbZero) {
        int t = b * 256 + tid;
        if (t < nZero4) *(int4*)&zeroInts[(long)t * 4] = make_int4(0, 0, 0, 0);
        return;
    }
    b -= nbZero;
    int t = b * 256 + tid;
    if (t < 512) *(float4*)&stats[(long)t * 4] = make_float4(0, 0, 0, 0);
}

// ======== BN params folded into activation: bf16 -> bf16, 16B/lane, fixed channels/thread ========
template<int LOGN>
__global__ __launch_bounds__(256) void bnact_bf16(
    const ushort* __restrict__ X,
    const float* __restrict__ sums, const float* __restrict__ sqs,
    const float* __restrict__ gamma, const float* __restrict__ beta, float invM,
    ushort* __restrict__ O, int nRows, int outStride, float negSlope)
{
    constexpr int NCH = 1 << LOGN;
    __shared__ float ssc[NCH], ssh[NCH];
    int tid = threadIdx.x;
    if (tid < NCH) {
        float mean = sums[tid] * invM;
        float var = sqs[tid] * invM - mean * mean;
        float sc = gamma[tid] * rsqrtf(var + BN_EPS);
        ssc[tid] = sc;
        ssh[tid] = beta[tid] - mean * sc;
    }
    __syncthreads();
    int cb = (tid * 8) & (NCH - 1);
    float4 sA = *(const float4*)&ssc[cb];
    float4 sB = *(const float4*)&ssc[cb + 4];
    float4 hA = *(const float4*)&ssh[cb];
    float4 hB = *(const float4*)&ssh[cb + 4];
    const int rpb = (256 * 8) >> LOGN;            // rows per block pass
    int r0 = blockIdx.x * rpb + ((tid * 8) >> LOGN);
    int rstride = gridDim.x * rpb;
    for (int row = r0; row < nRows; row += rstride) {
        us8 v = *(const us8*)&X[(long)row * NCH + cb];
        float f0 = bf2f(v[0]) * sA.x + hA.x; f0 = (f0 > 0.f) ? f0 : f0 * negSlope;
        float f1 = bf2f(v[1]) * sA.y + hA.y; f1 = (f1 > 0.f) ? f1 : f1 * negSlope;
        float f2 = bf2f(v[2]) * sA.z + hA.z; f2 = (f2 > 0.f) ? f2 : f2 * negSlope;
        float f3 = bf2f(v[3]) * sA.w + hA.w; f3 = (f3 > 0.f) ? f3 : f3 * negSlope;
        float f4 = bf2f(v[4]) * sB.x + hB.x; f4 = (f4 > 0.f) ? f4 : f4 * negSlope;
        float f5 = bf2f(v[5]) * sB.y + hB.y; f5 = (f5 > 0.f) ? f5 : f5 * negSlope;
        float f6 = bf2f(v[6]) * sB.z + hB.z; f6 = (f6 > 0.f) ? f6 : f6 * negSlope;
        float f7 = bf2f(v[7]) * sB.w + hB.w; f7 = (f7 > 0.f) ? f7 : f7 * negSlope;
        us8 o;
        o[0] = f2bf(f0); o[1] = f2bf(f1); o[2] = f2bf(f2); o[3] = f2bf(f3);
        o[4] = f2bf(f4); o[5] = f2bf(f5); o[6] = f2bf(f6); o[7] = f2bf(f7);
        *(us8*)&O[(long)row * outStride + cb] = o;
    }
}

// ======== BN params folded, fp32 in-place (final output, 128 ch) ========
__global__ __launch_bounds__(256) void bnact_f32(
    float* __restrict__ X,
    const float* __restrict__ sums, const float* __restrict__ sqs,
    const float* __restrict__ gamma, const float* __restrict__ beta, float invM,
    int nRows, float negSlope)
{
    __shared__ float ssc[128], ssh[128];
    int tid = threadIdx.x;
    if (tid < 128) {
        float mean = sums[tid] * invM;
        float var = sqs[tid] * invM - mean * mean;
        float sc = gamma[tid] * rsqrtf(var + BN_EPS);
        ssc[tid] = sc;
        ssh[tid] = beta[tid] - mean * sc;
    }
    __syncthreads();
    int cb = (tid * 4) & 127;
    float4 sc = *(const float4*)&ssc[cb];
    float4 sh = *(const float4*)&ssh[cb];
    int r0 = blockIdx.x * 8 + ((tid * 4) >> 7);
    int rstride = gridDim.x * 8;
    for (int row = r0; row < nRows; row += rstride) {
        float4 v = *(const float4*)&X[(long)row * 128 + cb];
        float a = v.x * sc.x + sh.x; a = (a > 0.f) ? a : a * negSlope;
        float b = v.y * sc.y + sh.y; b = (b > 0.f) ? b : b * negSlope;
        float d = v.z * sc.z + sh.z; d = (d > 0.f) ? d : d * negSlope;
        float e = v.w * sc.w + sh.w; e = (e > 0.f) ? e : e * negSlope;
        *(float4*)&X[(long)row * 128 + cb] = make_float4(a, b, d, e);
    }
}

// ======== column stats for final output (128 cols, register accum) ========
__global__ __launch_bounds__(256) void colstats128(
    const float* __restrict__ X, float* __restrict__ sums, float* __restrict__ sqs, int M)
{
    __shared__ float ss[128], sq[128];
    int tid = threadIdx.x;
    if (tid < 128) { ss[tid] = 0.f; sq[tid] = 0.f; }
    __syncthreads();
    int cg = tid & 31;
    int worker = (blockIdx.x << 3) | (tid >> 5);
    int totalW = gridDim.x << 3;
    float4 s4 = make_float4(0, 0, 0, 0), q4 = make_float4(0, 0, 0, 0);
    for (int r = worker; r < M; r += totalW) {
        float4 v = *(const float4*)&X[(long)r * 128 + cg * 4];
        s4.x += v.x; s4.y += v.y; s4.z += v.z; s4.w += v.w;
        q4.x += v.x * v.x; q4.y += v.y * v.y; q4.z += v.z * v.z; q4.w += v.w * v.w;
    }
    atomicAdd(&ss[cg * 4 + 0], s4.x); atomicAdd(&sq[cg * 4 + 0], q4.x);
    atomicAdd(&ss[cg * 4 + 1], s4.y); atomicAdd(&sq[cg * 4 + 1], q4.y);
    atomicAdd(&ss[cg * 4 + 2], s4.z); atomicAdd(&sq[cg * 4 + 2], q4.z);
    atomicAdd(&ss[cg * 4 + 3], s4.w); atomicAdd(&sq[cg * 4 + 3], q4.w);
    __syncthreads();
    if (tid < 128) { atomicAdd(&sums[tid], ss[tid]); atomicAdd(&sqs[tid], sq[tid]); }
}

// ======== CSR build ========
__global__ void degcount_kernel(const int* __restrict__ dst, int* __restrict__ degi, int E)
{
    int i = blockIdx.x * blockDim.x + threadIdx.x;
    if (i < E) atomicAdd(&degi[dst[i]], 1);
}

__global__ __launch_bounds__(256) void scan_block_sums(const int* __restrict__ degi,
                                                       int* __restrict__ partial, int n)
{
    __shared__ int s[256];
    int i = blockIdx.x * 256 + threadIdx.x;
    s[threadIdx.x] = (i < n) ? degi[i] : 0;
    __syncthreads();
    for (int off = 128; off > 0; off >>= 1) {
        if (threadIdx.x < off) s[threadIdx.x] += s[threadIdx.x + off];
        __syncthreads();
    }
    if (threadIdx.x == 0) partial[blockIdx.x] = s[0];
}

// scan_final also reduces the block-offset from raw per-block sums (scan_partials folded in)
__global__ __launch_bounds__(256) void scan_final(const int* __restrict__ degi,
                                                  const int* __restrict__ partial,
                                                  int* __restrict__ rowstart, int n, int nb)
{
    __shared__ int s[256];
    __shared__ int ps[256];
    int tid = threadIdx.x;
    ps[tid] = (tid < nb && tid < (int)blockIdx.x) ? partial[tid] : 0;
    __syncthreads();
    for (int off = 128; off > 0; off >>= 1) {
        if (tid < off) ps[tid] += ps[tid + off];
        __syncthreads();
    }
    int offset = ps[0];
    int i = blockIdx.x * 256 + tid;
    int v = (i < n) ? degi[i] : 0;
    s[tid] = v;
    __syncthreads();
    for (int off = 1; off < 256; off <<= 1) {
        int t = (tid >= off) ? s[tid - off] : 0;
        __syncthreads();
        s[tid] += t;
        __syncthreads();
    }
    if (i < n) rowstart[i] = offset + s[tid] - v;
}

__global__ void fillcsr_kernel(const int* __restrict__ src, const int* __restrict__ dst,
                               const int* __restrict__ rowstart, int* __restrict__ cursor,
                               int* __restrict__ csr, int E)
{
    int i = blockIdx.x * blockDim.x + threadIdx.x;
    if (i < E) {
        int d = dst[i];
        int p = atomicAdd(&cursor[d], 1);
        csr[rowstart[d] + p] = src[i];
    }
}

// ======== gather16: 16-lane group per edge, dwordx4 per lane (4 rows / wave-load) ========
__device__ __forceinline__ void acc8(float acc[8], us8 v) {
    #pragma unroll
    for (int e = 0; e < 8; e++) acc[e] += bf2f(v[e]);
}

// mean-gather bf16 -> bf16 (in: rows of X, 256-col stride, first 128 cols; out: O + wv*256)
__global__ __launch_bounds__(256) void gather16_bf(
    const ushort* __restrict__ X, const int* __restrict__ rowstart,
    const int* __restrict__ degi, const int* __restrict__ csr,
    ushort* __restrict__ O, int nN)
{
    int wv = (blockIdx.x * blockDim.x + threadIdx.x) >> 6;
    int lane = threadIdx.x & 63;
    if (wv >= nN) return;
    int g = lane >> 4;        // edge slot 0..3
    int sc = lane & 15;       // 16-B chunk of row
    int start = rowstart[wv], d = degi[wv];
    const ushort* Xc = X + sc * 8;
    float acc[8] = {};
    if (d > 0) {
        int dm = (d < 64) ? d : 64;
        int idx_l = csr[start + ((lane < dm) ? lane : (dm - 1))];
        int j = 0;
        for (; j + 8 <= dm; j += 8) {
            int i0 = __shfl(idx_l, j + g, 64);
            int i1 = __shfl(idx_l, j + 4 + g, 64);
            us8 v0 = *(const us8*)(Xc + (long)i0 * 256);
            us8 v1 = *(const us8*)(Xc + (long)i1 * 256);
            acc8(acc, v0);
            acc8(acc, v1);
        }
        if (j + 4 <= dm) {
            int i0 = __shfl(idx_l, j + g, 64);
            us8 v0 = *(const us8*)(Xc + (long)i0 * 256);
            acc8(acc, v0);
            j += 4;
        }
        int rem = dm - j;
        if (rem > 0) {
            int sl = j + ((g < rem) ? g : (rem - 1));
            int i0 = __shfl(idx_l, sl, 64);
            if (g < rem) {
                us8 v0 = *(const us8*)(Xc + (long)i0 * 256);
                acc8(acc, v0);
            }
        }
        for (int jj = 64; jj < d; jj += 4) {     // rare: degree > 64
            if (jj + g < d) {
                int i0 = csr[start + jj + g];
                us8 v0 = *(const us8*)(Xc + (long)i0 * 256);
                acc8(acc, v0);
            }
        }
    }
    #pragma unroll
    for (int e = 0; e < 8; e++) {
        acc[e] += __shfl_xor(acc[e], 16, 64);
        acc[e] += __shfl_xor(acc[e], 32, 64);
    }
    if (g == 0) {
        float inv = 1.f / fmaxf((float)d, 1.f);
        us8 o;
        #pragma unroll
        for (int e = 0; e < 8; e++) o[e] = f2bf(acc[e] * inv);
        *(us8*)(O + (long)wv * 256 + sc * 8) = o;
    }
}

// fused gather2: out = mean(Z[src, 0:128]) + Z[dst, 128:256]  (fp32 out, 128 cols)
__global__ __launch_bounds__(256) void gather16_fuse(
    const ushort* __restrict__ Z, const int* __restrict__ rowstart,
    const int* __restrict__ degi, const int* __restrict__ csr,
    float* __restrict__ O, int nN)
{
    int wv = (blockIdx.x * blockDim.x + threadIdx.x) >> 6;
    int lane = threadIdx.x & 63;
    if (wv >= nN) return;
    int g = lane >> 4;
    int sc = lane & 15;
    int start = rowstart[wv], d = degi[wv];
    const ushort* Zc = Z + sc * 8;
    us8 selfv = *(const us8*)(Zc + (long)wv * 256 + 128);   // independent, issued early
    float acc[8] = {};
    if (d > 0) {
        int dm = (d < 64) ? d : 64;
        int idx_l = csr[start + ((lane < dm) ? lane : (dm - 1))];
        int j = 0;
        for (; j + 8 <= dm; j += 8) {
            int i0 = __shfl(idx_l, j + g, 64);
            int i1 = __shfl(idx_l, j + 4 + g, 64);
            us8 v0 = *(const us8*)(Zc + (long)i0 * 256);
            us8 v1 = *(const us8*)(Zc + (long)i1 * 256);
            acc8(acc, v0);
            acc8(acc, v1);
        }
        if (j + 4 <= dm) {
            int i0 = __shfl(idx_l, j + g, 64);
            us8 v0 = *(const us8*)(Zc + (long)i0 * 256);
            acc8(acc, v0);
            j += 4;
        }
        int rem = dm - j;
        if (rem > 0) {
            int sl = j + ((g < rem) ? g : (rem - 1));
            int i0 = __shfl(idx_l, sl, 64);
            if (g < rem) {
                us8 v0 = *(const us8*)(Zc + (long)i0 * 256);
                acc8(acc, v0);
            }
        }
        for (int jj = 64; jj < d; jj += 4) {
            if (jj + g < d) {
                int i0 = csr[start + jj + g];
                us8 v0 = *(const us8*)(Zc + (long)i0 * 256);
                acc8(acc, v0);
            }
        }
    }
    #pragma unroll
    for (int e = 0; e < 8; e++) {
        acc[e] += __shfl_xor(acc[e], 16, 64);
        acc[e] += __shfl_xor(acc[e], 32, 64);
    }
    if (g == 0) {
        float inv = 1.f / fmaxf((float)d, 1.f);
        float r[8];
        #pragma unroll
        for (int e = 0; e < 8; e++) r[e] = acc[e] * inv + bf2f(selfv[e]);
        float* op = O + (long)wv * 128 + sc * 8;
        *(float4*)op = make_float4(r[0], r[1], r[2], r[3]);
        *(float4*)(op + 4) = make_float4(r[4], r[5], r[6], r[7]);
    }
}

extern "C" void kernel_launch(void* const* d_in, const int* in_sizes, int n_in,
                              void* d_out, int out_size, void* d_ws, size_t ws_size,
                              hipStream_t stream)
{
    const float* nodes = (const float*)d_in[0];
    const int*   src   = (const int*)d_in[1];
    const int*   dst   = (const int*)d_in[2];
    const float* Wf1   = (const float*)d_in[3];
    const float* gf1   = (const float*)d_in[5];
    const float* bef1  = (const float*)d_in[6];
    const float* Wf2   = (const float*)d_in[7];
    const float* gf2   = (const float*)d_in[9];
    const float* bef2  = (const float*)d_in[10];
    const float* Ws1   = (const float*)d_in[11];
    const float* Wn1   = (const float*)d_in[12];
    const float* gs1   = (const float*)d_in[14];
    const float* bs1   = (const float*)d_in[15];
    const float* Ws2   = (const float*)d_in[16];
    const float* Wn2   = (const float*)d_in[17];
    const float* gs2   = (const float*)d_in[19];
    const float* bs2   = (const float*)d_in[20];
    // pre-BN biases (bf1,bf2,b1,b2) cancel under BatchNorm -> skipped

    int nN = in_sizes[0] / DIN;   // 50000
    int nE = in_sizes[1];         // 600000
    float* out = (float*)d_out;
    int mStrips = nN / 16;        // 3125 (exact)
    float invM = 1.0f / nN;

    // ---- workspace (identical layout to passing version) ----
    ushort* PRE = (ushort*)d_ws;                      // nN*256 bf16 pre-BN GEMM out
    ushort* BF1 = PRE + (size_t)nN * 256;             // nN*256 bf16 (Xn / X1 / h1)
    ushort* BF2 = BF1 + (size_t)nN * 256;             // nN*256 bf16 ([h|agg] / Z)
    float* stats = (float*)(BF2 + (size_t)nN * 256);  // 2048 floats, 4 layer-regions
    float* scale = stats + 2048;                      // 256 (unused, kept for layout)
    float* shift = scale + 256;                       // 256 (unused, kept for layout)
    ushort* WT   = (ushort*)(shift + 256);            // 196608 shorts
    int* degi     = (int*)(WT + 196608);              // nN
    int* cursor   = degi + nN;                        // nN (adjacent: zeroed together)
    int* rowstart = cursor + nN;                      // nN
    int* partial  = rowstart + nN;                    // 256
    int* csr      = partial + 256;                    // nE

    ushort* Wf1T = WT;
    ushort* Wf2T = WT + 32768;
    ushort* Wc1T = WT + 65536;
    ushort* Wc2T = WT + 131072;

    dim3 blk(256);
    auto cdiv = [](int a, int b) { return (a + b - 1) / b; };
    int nScanBlocks = cdiv(nN, 256);                  // 196 (must be <= 256)

    // ---- fused setup: convert + weight transpose + zero stats/degi/cursor ----
    int nConv4 = nN * DIN / 4;
    int nbConv = cdiv(nConv4, 256);
    int nZero4 = (2 * nN) / 4;
    int nbZero = cdiv(nZero4, 256);
    setup_all<<<dim3(nbConv + 768 + nbZero + 2), blk, 0, stream>>>(
        nodes, BF1, nConv4, nbConv,
        Wf1, Wf2, Ws1, Wn1, Wn2, Ws2, WT,
        degi, nZero4, nbZero, stats);

    // ---- CSR build ----
    degcount_kernel<<<dim3(cdiv(nE, 256)), blk, 0, stream>>>(dst, degi, nE);
    scan_block_sums<<<dim3(nScanBlocks), blk, 0, stream>>>(degi, partial, nN);
    scan_final<<<dim3(nScanBlocks), blk, 0, stream>>>(degi, partial, rowstart, nN, nScanBlocks);
    fillcsr_kernel<<<dim3(cdiv(nE, 256)), blk, 0, stream>>>(src, dst, rowstart, cursor, csr, nE);

    // ---- FF1: PRE = Xn @ Wf1T (K=128, N=256, NT=4, stats->L0) ; fused BN+ReLU -> BF1 ----
    gemm_wreg<4, 4, 1><<<dim3(512), blk, 0, stream>>>(BF1, Wf1T, PRE, mStrips, 256, 128, 2, stats, stats + 256);
    bnact_bf16<8><<<dim3(2048), blk, 0, stream>>>(PRE, stats, stats + 256, gf1, bef1, invM,
                                                  BF1, nN, 256, 0.0f);

    // ---- FF2: PRE = BF1 @ Wf2T (K=256, N=128, NT=2 -> 4 groups, stats->L1) ; fused BN+ReLU -> BF2[:,0:128] ----
    gemm_wreg<8, 2, 1><<<dim3(512), blk, 0, stream>>>(BF1, Wf2T, PRE, mStrips, 128, 256, 2, stats + 512, stats + 768);
    bnact_bf16<7><<<dim3(2048), blk, 0, stream>>>(PRE, stats + 512, stats + 768, gf2, bef2, invM,
                                                  BF2, nN, 256, 0.0f);

    // ---- gather1: BF2[:,128:256] = mean-gather(BF2[:,0:128]) ----
    gather16_bf<<<dim3(cdiv(nN * 64, 256)), blk, 0, stream>>>(BF2, rowstart, degi, csr, BF2 + 128, nN);

    // ---- SAGE1: PRE = [h|agg] @ [Ws1;Wn1] (K=256, N=256, NT=2 -> 8 groups, stats->L2) ; BN+LReLU -> BF1 ----
    gemm_wreg<8, 2, 1><<<dim3(1024), blk, 0, stream>>>(BF2, Wc1T, PRE, mStrips, 256, 256, 3, stats + 1024, stats + 1280);
    bnact_bf16<8><<<dim3(2048), blk, 0, stream>>>(PRE, stats + 1024, stats + 1280, gs1, bs1, invM,
                                                  BF1, nN, 256, 0.01f);

    // ---- SAGE2: BF2 = h1 @ [Wn2|Ws2] (K=256, N=256, NT=2, no stats) ; gather16_fuse -> out(fp32) ----
    gemm_wreg<8, 2, 0><<<dim3(1024), blk, 0, stream>>>(BF1, Wc2T, BF2, mStrips, 256, 256, 3, nullptr, nullptr);
    gather16_fuse<<<dim3(cdiv(nN * 64, 256)), blk, 0, stream>>>(BF2, rowstart, degi, csr, out, nN);

    // ---- final: colstats -> fused BN+LReLU on out ----
    colstats128<<<dim3(120), blk, 0, stream>>>(out, stats + 1536, stats + 1792, nN);
    bnact_f32<<<dim3(2048), blk, 0, stream>>>(out, stats + 1536, stats + 1792, gs2, bs2, invM,
                                              nN, 0.01f);
}

// Round 6
// 372.315 us; speedup vs baseline: 1.0929x; 1.0929x over previous
//
#include <hip/hip_runtime.h>

#define DIN 128
#define BN_EPS 1e-5f

typedef __attribute__((ext_vector_type(8))) short bf16x8;
typedef __attribute__((ext_vector_type(8))) unsigned short us8;
typedef __attribute__((ext_vector_type(4))) float f32x4;

__device__ __forceinline__ ushort f2bf(float f) {
    unsigned u = __float_as_uint(f);
    u += 0x7fffu + ((u >> 16) & 1u);
    return (ushort)(u >> 16);
}
__device__ __forceinline__ float bf2f(ushort h) {
    return __uint_as_float(((unsigned)h) << 16);
}

// ======== LDS-shared streaming GEMM: C[M,N](bf16) = A[M,K](bf16) @ BT[N,K]^T ========
// One block covers ALL N columns (4 waves x NT 16-col tiles). The 16-row A strip
// (contiguous 4-8KB) is staged ONCE per block into LDS (was: re-read scattered by
// every col-group wave -> redundant HBM-latency stalls, R5 diagnosis).
// T14 split: next strip's global loads issued BEFORE compute, ds_write AFTER barrier.
// LDS chunks XOR-swizzled (c ^= r&7, 16B granule) -> ds_read_b128 at data-floor rate.
template<int KC, int NT, int STATS>
__global__ __launch_bounds__(256) void gemm_lds(
    const ushort* __restrict__ A, const ushort* __restrict__ BT,
    ushort* __restrict__ C, int mStrips, int N,
    float* __restrict__ gsums, float* __restrict__ gsqs)
{
    constexpr int K = KC * 32;           // K in shorts
    constexpr int CPR = KC * 4;          // 16B chunks per row
    constexpr int LOGCPR = (KC == 4) ? 4 : 5;
    constexpr int LPL = KC / 4;          // staging loads per lane per strip (1 or 2)
    __shared__ ushort abuf[16 * K];      // one 16-row strip (4KB / 8KB)

    int tid = threadIdx.x;
    int lane = tid & 63;
    int w = tid >> 6;                    // wave id 0..3 -> col tile
    int cl = lane & 15, q = lane >> 4;
    int colBase = w * (16 * NT);
    int chBase = w * (16 * KC);          // this wave's staging chunk range

    // B fragments: loaded once per kernel (weights are L2-resident)
    bf16x8 bf[NT][KC];
    #pragma unroll
    for (int nt = 0; nt < NT; nt++) {
        const ushort* bp = BT + (long)(colBase + nt * 16 + cl) * K + q * 8;
        #pragma unroll
        for (int kc = 0; kc < KC; kc++)
            bf[nt][kc] = *(const bf16x8*)(bp + kc * 32);
    }

    float ssum[NT], ssq[NT];
    #pragma unroll
    for (int nt = 0; nt < NT; nt++) { ssum[nt] = 0.f; ssq[nt] = 0.f; }

    int totalSets = gridDim.x;
    int s0 = blockIdx.x;

    us8 stg[LPL];
    // ---- prologue: stage strip s0 (linear coalesced load, swizzled LDS write) ----
    {
        const ushort* As = A + (long)s0 * 16 * K;
        #pragma unroll
        for (int u = 0; u < LPL; u++)
            stg[u] = *(const us8*)(As + (chBase + u * 64 + lane) * 8);
        #pragma unroll
        for (int u = 0; u < LPL; u++) {
            int ch = chBase + u * 64 + lane;
            int r = ch >> LOGCPR;
            int c = ch & (CPR - 1);
            *(us8*)(abuf + (((r << LOGCPR) + (c ^ (r & 7))) * 8)) = stg[u];
        }
    }
    __syncthreads();

    for (int s = s0; s < mStrips; s += totalSets) {
        int nxt = s + totalSets;
        bool more = nxt < mStrips;       // block-uniform
        if (more) {                      // T14: issue loads EARLY, consume late
            const ushort* As = A + (long)nxt * 16 * K;
            #pragma unroll
            for (int u = 0; u < LPL; u++)
                stg[u] = *(const us8*)(As + (chBase + u * 64 + lane) * 8);
        }
        // A fragments from LDS (swizzled chunk addressing)
        bf16x8 af[KC];
        #pragma unroll
        for (int kc = 0; kc < KC; kc++)
            af[kc] = *(const bf16x8*)(abuf + (((cl << LOGCPR) + ((kc * 4 + q) ^ (cl & 7))) * 8));
        f32x4 acc[NT] = {};
        #pragma unroll
        for (int kc = 0; kc < KC; kc++)
            #pragma unroll
            for (int nt = 0; nt < NT; nt++)
                acc[nt] = __builtin_amdgcn_mfma_f32_16x16x32_bf16(af[kc], bf[nt][kc], acc[nt], 0, 0, 0);
        int rowBase = s * 16;
        #pragma unroll
        for (int nt = 0; nt < NT; nt++) {
            #pragma unroll
            for (int r = 0; r < 4; r++) {
                float v = acc[nt][r];
                long row = rowBase + q * 4 + r;
                C[row * N + colBase + nt * 16 + cl] = f2bf(v);
                if (STATS) { ssum[nt] += v; ssq[nt] += v * v; }
            }
        }
        __syncthreads();                 // all waves done reading abuf
        if (more) {
            #pragma unroll
            for (int u = 0; u < LPL; u++) {
                int ch = chBase + u * 64 + lane;
                int r = ch >> LOGCPR;
                int c = ch & (CPR - 1);
                *(us8*)(abuf + (((r << LOGCPR) + (c ^ (r & 7))) * 8)) = stg[u];
            }
        }
        __syncthreads();                 // abuf ready for next iter
    }

    if (STATS) {
        #pragma unroll
        for (int nt = 0; nt < NT; nt++) {
            ssum[nt] += __shfl_xor(ssum[nt], 16, 64);
            ssum[nt] += __shfl_xor(ssum[nt], 32, 64);
            ssq[nt]  += __shfl_xor(ssq[nt], 16, 64);
            ssq[nt]  += __shfl_xor(ssq[nt], 32, 64);
        }
        if (q == 0) {
            #pragma unroll
            for (int nt = 0; nt < NT; nt++) {
                atomicAdd(&gsums[colBase + nt * 16 + cl], ssum[nt]);
                atomicAdd(&gsqs[colBase + nt * 16 + cl], ssq[nt]);
            }
        }
    }
}

// ======== fused setup: convert nodes -> bf16, transpose weights, zero stats + degi/cursor ========
__global__ __launch_bounds__(256) void setup_all(
    const float* __restrict__ nodes, ushort* __restrict__ Xbf, int nConv4, int nbConv,
    const float* __restrict__ W0, const float* __restrict__ W1,
    const float* __restrict__ W2, const float* __restrict__ W3,
    const float* __restrict__ W4, const float* __restrict__ W5,
    ushort* __restrict__ WT,
    int* __restrict__ zeroInts, int nZero4, int nbZero,
    float* __restrict__ stats)
{
    int b = blockIdx.x;
    int tid = threadIdx.x;
    if (b < nbConv) {
        int t = b * 256 + tid;
        if (t < nConv4) {
            float4 v = *(const float4*)&nodes[(long)t * 4];
            ushort4 o; o.x = f2bf(v.x); o.y = f2bf(v.y); o.z = f2bf(v.z); o.w = f2bf(v.w);
            *(ushort4*)&Xbf[(long)t * 4] = o;
        }
        return;
    }
    b -= nbConv;
    if (b < 768) {
        int seg = b >> 7;
        const float* W; int logK, dstBase, stride, kOff;
        switch (seg) {
            case 0: W = W0; logK = 7; dstBase = 0;      stride = 128; kOff = 0;   break;
            case 1: W = W1; logK = 8; dstBase = 32768;  stride = 256; kOff = 0;   break;
            case 2: W = W2; logK = 7; dstBase = 65536;  stride = 256; kOff = 0;   break;
            case 3: W = W3; logK = 7; dstBase = 65536;  stride = 256; kOff = 128; break;
            case 4: W = W4; logK = 8; dstBase = 131072; stride = 256; kOff = 0;   break;
            default:W = W5; logK = 8; dstBase = 163840; stride = 256; kOff = 0;   break;
        }
        int t = (b & 127) * 256 + tid;
        int N = 32768 >> logK;
        int k = t & ((1 << logK) - 1);
        int n = t >> logK;
        WT[(long)dstBase + (long)n * stride + kOff + k] = f2bf(W[(long)k * N + n]);
        return;
    }
    b -= 768;
    if (b < nbZero) {
        int t = b * 256 + tid;
        if (t < nZero4) *(int4*)&zeroInts[(long)t * 4] = make_int4(0, 0, 0, 0);
        return;
    }
    b -= nbZero;
    int t = b * 256 + tid;
    if (t < 512) *(float4*)&stats[(long)t * 4] = make_float4(0, 0, 0, 0);
}

// ======== BN params folded into activation: bf16 -> bf16, 16B/lane, fixed channels/thread ========
template<int LOGN>
__global__ __launch_bounds__(256) void bnact_bf16(
    const ushort* __restrict__ X,
    const float* __restrict__ sums, const float* __restrict__ sqs,
    const float* __restrict__ gamma, const float* __restrict__ beta, float invM,
    ushort* __restrict__ O, int nRows, int outStride, float negSlope)
{
    constexpr int NCH = 1 << LOGN;
    __shared__ float ssc[NCH], ssh[NCH];
    int tid = threadIdx.x;
    if (tid < NCH) {
        float mean = sums[tid] * invM;
        float var = sqs[tid] * invM - mean * mean;
        float sc = gamma[tid] * rsqrtf(var + BN_EPS);
        ssc[tid] = sc;
        ssh[tid] = beta[tid] - mean * sc;
    }
    __syncthreads();
    int cb = (tid * 8) & (NCH - 1);
    float4 sA = *(const float4*)&ssc[cb];
    float4 sB = *(const float4*)&ssc[cb + 4];
    float4 hA = *(const float4*)&ssh[cb];
    float4 hB = *(const float4*)&ssh[cb + 4];
    const int rpb = (256 * 8) >> LOGN;            // rows per block pass
    int r0 = blockIdx.x * rpb + ((tid * 8) >> LOGN);
    int rstride = gridDim.x * rpb;
    for (int row = r0; row < nRows; row += rstride) {
        us8 v = *(const us8*)&X[(long)row * NCH + cb];
        float f0 = bf2f(v[0]) * sA.x + hA.x; f0 = (f0 > 0.f) ? f0 : f0 * negSlope;
        float f1 = bf2f(v[1]) * sA.y + hA.y; f1 = (f1 > 0.f) ? f1 : f1 * negSlope;
        float f2 = bf2f(v[2]) * sA.z + hA.z; f2 = (f2 > 0.f) ? f2 : f2 * negSlope;
        float f3 = bf2f(v[3]) * sA.w + hA.w; f3 = (f3 > 0.f) ? f3 : f3 * negSlope;
        float f4 = bf2f(v[4]) * sB.x + hB.x; f4 = (f4 > 0.f) ? f4 : f4 * negSlope;
        float f5 = bf2f(v[5]) * sB.y + hB.y; f5 = (f5 > 0.f) ? f5 : f5 * negSlope;
        float f6 = bf2f(v[6]) * sB.z + hB.z; f6 = (f6 > 0.f) ? f6 : f6 * negSlope;
        float f7 = bf2f(v[7]) * sB.w + hB.w; f7 = (f7 > 0.f) ? f7 : f7 * negSlope;
        us8 o;
        o[0] = f2bf(f0); o[1] = f2bf(f1); o[2] = f2bf(f2); o[3] = f2bf(f3);
        o[4] = f2bf(f4); o[5] = f2bf(f5); o[6] = f2bf(f6); o[7] = f2bf(f7);
        *(us8*)&O[(long)row * outStride + cb] = o;
    }
}

// ======== BN params folded, fp32 in-place (final output, 128 ch) ========
__global__ __launch_bounds__(256) void bnact_f32(
    float* __restrict__ X,
    const float* __restrict__ sums, const float* __restrict__ sqs,
    const float* __restrict__ gamma, const float* __restrict__ beta, float invM,
    int nRows, float negSlope)
{
    __shared__ float ssc[128], ssh[128];
    int tid = threadIdx.x;
    if (tid < 128) {
        float mean = sums[tid] * invM;
        float var = sqs[tid] * invM - mean * mean;
        float sc = gamma[tid] * rsqrtf(var + BN_EPS);
        ssc[tid] = sc;
        ssh[tid] = beta[tid] - mean * sc;
    }
    __syncthreads();
    int cb = (tid * 4) & 127;
    float4 sc = *(const float4*)&ssc[cb];
    float4 sh = *(const float4*)&ssh[cb];
    int r0 = blockIdx.x * 8 + ((tid * 4) >> 7);
    int rstride = gridDim.x * 8;
    for (int row = r0; row < nRows; row += rstride) {
        float4 v = *(const float4*)&X[(long)row * 128 + cb];
        float a = v.x * sc.x + sh.x; a = (a > 0.f) ? a : a * negSlope;
        float b = v.y * sc.y + sh.y; b = (b > 0.f) ? b : b * negSlope;
        float d = v.z * sc.z + sh.z; d = (d > 0.f) ? d : d * negSlope;
        float e = v.w * sc.w + sh.w; e = (e > 0.f) ? e : e * negSlope;
        *(float4*)&X[(long)row * 128 + cb] = make_float4(a, b, d, e);
    }
}

// ======== column stats for final output (128 cols, register accum) ========
__global__ __launch_bounds__(256) void colstats128(
    const float* __restrict__ X, float* __restrict__ sums, float* __restrict__ sqs, int M)
{
    __shared__ float ss[128], sq[128];
    int tid = threadIdx.x;
    if (tid < 128) { ss[tid] = 0.f; sq[tid] = 0.f; }
    __syncthreads();
    int cg = tid & 31;
    int worker = (blockIdx.x << 3) | (tid >> 5);
    int totalW = gridDim.x << 3;
    float4 s4 = make_float4(0, 0, 0, 0), q4 = make_float4(0, 0, 0, 0);
    for (int r = worker; r < M; r += totalW) {
        float4 v = *(const float4*)&X[(long)r * 128 + cg * 4];
        s4.x += v.x; s4.y += v.y; s4.z += v.z; s4.w += v.w;
        q4.x += v.x * v.x; q4.y += v.y * v.y; q4.z += v.z * v.z; q4.w += v.w * v.w;
    }
    atomicAdd(&ss[cg * 4 + 0], s4.x); atomicAdd(&sq[cg * 4 + 0], q4.x);
    atomicAdd(&ss[cg * 4 + 1], s4.y); atomicAdd(&sq[cg * 4 + 1], q4.y);
    atomicAdd(&ss[cg * 4 + 2], s4.z); atomicAdd(&sq[cg * 4 + 2], q4.z);
    atomicAdd(&ss[cg * 4 + 3], s4.w); atomicAdd(&sq[cg * 4 + 3], q4.w);
    __syncthreads();
    if (tid < 128) { atomicAdd(&sums[tid], ss[tid]); atomicAdd(&sqs[tid], sq[tid]); }
}

// ======== CSR build ========
__global__ void degcount_kernel(const int* __restrict__ dst, int* __restrict__ degi, int E)
{
    int i = blockIdx.x * blockDim.x + threadIdx.x;
    if (i < E) atomicAdd(&degi[dst[i]], 1);
}

__global__ __launch_bounds__(256) void scan_block_sums(const int* __restrict__ degi,
                                                       int* __restrict__ partial, int n)
{
    __shared__ int s[256];
    int i = blockIdx.x * 256 + threadIdx.x;
    s[threadIdx.x] = (i < n) ? degi[i] : 0;
    __syncthreads();
    for (int off = 128; off > 0; off >>= 1) {
        if (threadIdx.x < off) s[threadIdx.x] += s[threadIdx.x + off];
        __syncthreads();
    }
    if (threadIdx.x == 0) partial[blockIdx.x] = s[0];
}

// scan_final also reduces the block-offset from raw per-block sums (scan_partials folded in)
__global__ __launch_bounds__(256) void scan_final(const int* __restrict__ degi,
                                                  const int* __restrict__ partial,
                                                  int* __restrict__ rowstart, int n, int nb)
{
    __shared__ int s[256];
    __shared__ int ps[256];
    int tid = threadIdx.x;
    ps[tid] = (tid < nb && tid < (int)blockIdx.x) ? partial[tid] : 0;
    __syncthreads();
    for (int off = 128; off > 0; off >>= 1) {
        if (tid < off) ps[tid] += ps[tid + off];
        __syncthreads();
    }
    int offset = ps[0];
    int i = blockIdx.x * 256 + tid;
    int v = (i < n) ? degi[i] : 0;
    s[tid] = v;
    __syncthreads();
    for (int off = 1; off < 256; off <<= 1) {
        int t = (tid >= off) ? s[tid - off] : 0;
        __syncthreads();
        s[tid] += t;
        __syncthreads();
    }
    if (i < n) rowstart[i] = offset + s[tid] - v;
}

__global__ void fillcsr_kernel(const int* __restrict__ src, const int* __restrict__ dst,
                               const int* __restrict__ rowstart, int* __restrict__ cursor,
                               int* __restrict__ csr, int E)
{
    int i = blockIdx.x * blockDim.x + threadIdx.x;
    if (i < E) {
        int d = dst[i];
        int p = atomicAdd(&cursor[d], 1);
        csr[rowstart[d] + p] = src[i];
    }
}

// ======== gather16: 16-lane group per edge, dwordx4 per lane (4 rows / wave-load) ========
__device__ __forceinline__ void acc8(float acc[8], us8 v) {
    #pragma unroll
    for (int e = 0; e < 8; e++) acc[e] += bf2f(v[e]);
}

// mean-gather bf16 -> bf16 (in: rows of X, 256-col stride, first 128 cols; out: O + wv*256)
__global__ __launch_bounds__(256) void gather16_bf(
    const ushort* __restrict__ X, const int* __restrict__ rowstart,
    const int* __restrict__ degi, const int* __restrict__ csr,
    ushort* __restrict__ O, int nN)
{
    int wv = (blockIdx.x * blockDim.x + threadIdx.x) >> 6;
    int lane = threadIdx.x & 63;
    if (wv >= nN) return;
    int g = lane >> 4;        // edge slot 0..3
    int sc = lane & 15;       // 16-B chunk of row
    int start = rowstart[wv], d = degi[wv];
    const ushort* Xc = X + sc * 8;
    float acc[8] = {};
    if (d > 0) {
        int dm = (d < 64) ? d : 64;
        int idx_l = csr[start + ((lane < dm) ? lane : (dm - 1))];
        int j = 0;
        for (; j + 8 <= dm; j += 8) {
            int i0 = __shfl(idx_l, j + g, 64);
            int i1 = __shfl(idx_l, j + 4 + g, 64);
            us8 v0 = *(const us8*)(Xc + (long)i0 * 256);
            us8 v1 = *(const us8*)(Xc + (long)i1 * 256);
            acc8(acc, v0);
            acc8(acc, v1);
        }
        if (j + 4 <= dm) {
            int i0 = __shfl(idx_l, j + g, 64);
            us8 v0 = *(const us8*)(Xc + (long)i0 * 256);
            acc8(acc, v0);
            j += 4;
        }
        int rem = dm - j;
        if (rem > 0) {
            int sl = j + ((g < rem) ? g : (rem - 1));
            int i0 = __shfl(idx_l, sl, 64);
            if (g < rem) {
                us8 v0 = *(const us8*)(Xc + (long)i0 * 256);
                acc8(acc, v0);
            }
        }
        for (int jj = 64; jj < d; jj += 4) {     // rare: degree > 64
            if (jj + g < d) {
                int i0 = csr[start + jj + g];
                us8 v0 = *(const us8*)(Xc + (long)i0 * 256);
                acc8(acc, v0);
            }
        }
    }
    #pragma unroll
    for (int e = 0; e < 8; e++) {
        acc[e] += __shfl_xor(acc[e], 16, 64);
        acc[e] += __shfl_xor(acc[e], 32, 64);
    }
    if (g == 0) {
        float inv = 1.f / fmaxf((float)d, 1.f);
        us8 o;
        #pragma unroll
        for (int e = 0; e < 8; e++) o[e] = f2bf(acc[e] * inv);
        *(us8*)(O + (long)wv * 256 + sc * 8) = o;
    }
}

// fused gather2: out = mean(Z[src, 0:128]) + Z[dst, 128:256]  (fp32 out, 128 cols)
__global__ __launch_bounds__(256) void gather16_fuse(
    const ushort* __restrict__ Z, const int* __restrict__ rowstart,
    const int* __restrict__ degi, const int* __restrict__ csr,
    float* __restrict__ O, int nN)
{
    int wv = (blockIdx.x * blockDim.x + threadIdx.x) >> 6;
    int lane = threadIdx.x & 63;
    if (wv >= nN) return;
    int g = lane >> 4;
    int sc = lane & 15;
    int start = rowstart[wv], d = degi[wv];
    const ushort* Zc = Z + sc * 8;
    us8 selfv = *(const us8*)(Zc + (long)wv * 256 + 128);   // independent, issued early
    float acc[8] = {};
    if (d > 0) {
        int dm = (d < 64) ? d : 64;
        int idx_l = csr[start + ((lane < dm) ? lane : (dm - 1))];
        int j = 0;
        for (; j + 8 <= dm; j += 8) {
            int i0 = __shfl(idx_l, j + g, 64);
            int i1 = __shfl(idx_l, j + 4 + g, 64);
            us8 v0 = *(const us8*)(Zc + (long)i0 * 256);
            us8 v1 = *(const us8*)(Zc + (long)i1 * 256);
            acc8(acc, v0);
            acc8(acc, v1);
        }
        if (j + 4 <= dm) {
            int i0 = __shfl(idx_l, j + g, 64);
            us8 v0 = *(const us8*)(Zc + (long)i0 * 256);
            acc8(acc, v0);
            j += 4;
        }
        int rem = dm - j;
        if (rem > 0) {
            int sl = j + ((g < rem) ? g : (rem - 1));
            int i0 = __shfl(idx_l, sl, 64);
            if (g < rem) {
                us8 v0 = *(const us8*)(Zc + (long)i0 * 256);
                acc8(acc, v0);
            }
        }
        for (int jj = 64; jj < d; jj += 4) {
            if (jj + g < d) {
                int i0 = csr[start + jj + g];
                us8 v0 = *(const us8*)(Zc + (long)i0 * 256);
                acc8(acc, v0);
            }
        }
    }
    #pragma unroll
    for (int e = 0; e < 8; e++) {
        acc[e] += __shfl_xor(acc[e], 16, 64);
        acc[e] += __shfl_xor(acc[e], 32, 64);
    }
    if (g == 0) {
        float inv = 1.f / fmaxf((float)d, 1.f);
        float r[8];
        #pragma unroll
        for (int e = 0; e < 8; e++) r[e] = acc[e] * inv + bf2f(selfv[e]);
        float* op = O + (long)wv * 128 + sc * 8;
        *(float4*)op = make_float4(r[0], r[1], r[2], r[3]);
        *(float4*)(op + 4) = make_float4(r[4], r[5], r[6], r[7]);
    }
}

extern "C" void kernel_launch(void* const* d_in, const int* in_sizes, int n_in,
                              void* d_out, int out_size, void* d_ws, size_t ws_size,
                              hipStream_t stream)
{
    const float* nodes = (const float*)d_in[0];
    const int*   src   = (const int*)d_in[1];
    const int*   dst   = (const int*)d_in[2];
    const float* Wf1   = (const float*)d_in[3];
    const float* gf1   = (const float*)d_in[5];
    const float* bef1  = (const float*)d_in[6];
    const float* Wf2   = (const float*)d_in[7];
    const float* gf2   = (const float*)d_in[9];
    const float* bef2  = (const float*)d_in[10];
    const float* Ws1   = (const float*)d_in[11];
    const float* Wn1   = (const float*)d_in[12];
    const float* gs1   = (const float*)d_in[14];
    const float* bs1   = (const float*)d_in[15];
    const float* Ws2   = (const float*)d_in[16];
    const float* Wn2   = (const float*)d_in[17];
    const float* gs2   = (const float*)d_in[19];
    const float* bs2   = (const float*)d_in[20];
    // pre-BN biases (bf1,bf2,b1,b2) cancel under BatchNorm -> skipped

    int nN = in_sizes[0] / DIN;   // 50000
    int nE = in_sizes[1];         // 600000
    float* out = (float*)d_out;
    int mStrips = nN / 16;        // 3125 (exact)
    float invM = 1.0f / nN;

    // ---- workspace (identical layout to passing version) ----
    ushort* PRE = (ushort*)d_ws;                      // nN*256 bf16 pre-BN GEMM out
    ushort* BF1 = PRE + (size_t)nN * 256;             // nN*256 bf16 (Xn / X1 / h1)
    ushort* BF2 = BF1 + (size_t)nN * 256;             // nN*256 bf16 ([h|agg] / Z)
    float* stats = (float*)(BF2 + (size_t)nN * 256);  // 2048 floats, 4 layer-regions
    float* scale = stats + 2048;                      // 256 (unused, kept for layout)
    float* shift = scale + 256;                       // 256 (unused, kept for layout)
    ushort* WT   = (ushort*)(shift + 256);            // 196608 shorts
    int* degi     = (int*)(WT + 196608);              // nN
    int* cursor   = degi + nN;                        // nN (adjacent: zeroed together)
    int* rowstart = cursor + nN;                      // nN
    int* partial  = rowstart + nN;                    // 256
    int* csr      = partial + 256;                    // nE

    ushort* Wf1T = WT;
    ushort* Wf2T = WT + 32768;
    ushort* Wc1T = WT + 65536;
    ushort* Wc2T = WT + 131072;

    dim3 blk(256);
    auto cdiv = [](int a, int b) { return (a + b - 1) / b; };
    int nScanBlocks = cdiv(nN, 256);                  // 196 (must be <= 256)

    // ---- fused setup: convert + weight transpose + zero stats/degi/cursor ----
    int nConv4 = nN * DIN / 4;
    int nbConv = cdiv(nConv4, 256);
    int nZero4 = (2 * nN) / 4;
    int nbZero = cdiv(nZero4, 256);
    setup_all<<<dim3(nbConv + 768 + nbZero + 2), blk, 0, stream>>>(
        nodes, BF1, nConv4, nbConv,
        Wf1, Wf2, Ws1, Wn1, Wn2, Ws2, WT,
        degi, nZero4, nbZero, stats);

    // ---- CSR build ----
    degcount_kernel<<<dim3(cdiv(nE, 256)), blk, 0, stream>>>(dst, degi, nE);
    scan_block_sums<<<dim3(nScanBlocks), blk, 0, stream>>>(degi, partial, nN);
    scan_final<<<dim3(nScanBlocks), blk, 0, stream>>>(degi, partial, rowstart, nN, nScanBlocks);
    fillcsr_kernel<<<dim3(cdiv(nE, 256)), blk, 0, stream>>>(src, dst, rowstart, cursor, csr, nE);

    // ---- FF1: PRE = Xn @ Wf1T (K=128, N=256, stats->L0) ; fused BN+ReLU -> BF1 ----
    gemm_lds<4, 4, 1><<<dim3(512), blk, 0, stream>>>(BF1, Wf1T, PRE, mStrips, 256, stats, stats + 256);
    bnact_bf16<8><<<dim3(2048), blk, 0, stream>>>(PRE, stats, stats + 256, gf1, bef1, invM,
                                                  BF1, nN, 256, 0.0f);

    // ---- FF2: PRE = BF1 @ Wf2T (K=256, N=128, stats->L1) ; fused BN+ReLU -> BF2[:,0:128] ----
    gemm_lds<8, 2, 1><<<dim3(512), blk, 0, stream>>>(BF1, Wf2T, PRE, mStrips, 128, stats + 512, stats + 768);
    bnact_bf16<7><<<dim3(2048), blk, 0, stream>>>(PRE, stats + 512, stats + 768, gf2, bef2, invM,
                                                  BF2, nN, 256, 0.0f);

    // ---- gather1: BF2[:,128:256] = mean-gather(BF2[:,0:128]) ----
    gather16_bf<<<dim3(cdiv(nN * 64, 256)), blk, 0, stream>>>(BF2, rowstart, degi, csr, BF2 + 128, nN);

    // ---- SAGE1: PRE = [h|agg] @ [Ws1;Wn1] (K=256, N=256, stats->L2) ; BN+LReLU -> BF1 ----
    gemm_lds<8, 4, 1><<<dim3(512), blk, 0, stream>>>(BF2, Wc1T, PRE, mStrips, 256, stats + 1024, stats + 1280);
    bnact_bf16<8><<<dim3(2048), blk, 0, stream>>>(PRE, stats + 1024, stats + 1280, gs1, bs1, invM,
                                                  BF1, nN, 256, 0.01f);

    // ---- SAGE2: BF2 = h1 @ [Wn2|Ws2] (K=256, N=256, no stats) ; gather16_fuse -> out(fp32) ----
    gemm_lds<8, 4, 0><<<dim3(512), blk, 0, stream>>>(BF1, Wc2T, BF2, mStrips, 256, nullptr, nullptr);
    gather16_fuse<<<dim3(cdiv(nN * 64, 256)), blk, 0, stream>>>(BF2, rowstart, degi, csr, out, nN);

    // ---- final: colstats -> fused BN+LReLU on out ----
    colstats128<<<dim3(120), blk, 0, stream>>>(out, stats + 1536, stats + 1792, nN);
    bnact_f32<<<dim3(2048), blk, 0, stream>>>(out, stats + 1536, stats + 1792, gs2, bs2, invM,
                                              nN, 0.01f);
}

// Round 7
// 355.548 us; speedup vs baseline: 1.1445x; 1.0472x over previous
//
#include <hip/hip_runtime.h>

#define DIN 128
#define BN_EPS 1e-5f

typedef __attribute__((ext_vector_type(8))) short bf16x8;
typedef __attribute__((ext_vector_type(8))) unsigned short us8;
typedef __attribute__((ext_vector_type(4))) float f32x4;

__device__ __forceinline__ ushort f2bf(float f) {
    unsigned u = __float_as_uint(f);
    u += 0x7fffu + ((u >> 16) & 1u);
    return (ushort)(u >> 16);
}
__device__ __forceinline__ float bf2f(ushort h) {
    return __uint_as_float(((unsigned)h) << 16);
}

// ======== LDS-shared streaming GEMM v2: C[M,N](bf16) = A[M,K](bf16) @ BT[N,K]^T ========
// R6 base (block-shared A strip in LDS, +34us win) plus:
//  - double-buffered LDS + depth-2 register prefetch (stgA/stgB parity-unrolled, no
//    runtime-indexed reg arrays), 1 barrier per strip instead of 2; ds_write consumes
//    data loaded a full iteration earlier (HBM latency fully covered).
//  - BNIN: fold BN+activation of the PREVIOUS layer into the A-staging transform
//    (reads raw PRE, applies per-channel scale/shift+act, writes bf16 to LDS).
//    Bit-identical to the separate bnact pass (same fp32 formula, same rounding).
//    Lane's staging chunks share one K-column -> 8 sc/sh values, prologue-computed.
template<int KC, int NT, int LOGNG, int STATS, int BNIN>
__global__ __launch_bounds__(256) void gemm_lds(
    const ushort* __restrict__ A, const ushort* __restrict__ BT,
    ushort* __restrict__ C, int mStrips, int N,
    float* __restrict__ gsums, float* __restrict__ gsqs,
    const float* __restrict__ isums, const float* __restrict__ isqs,
    const float* __restrict__ igam, const float* __restrict__ ibet,
    float invM, float negSlope)
{
    constexpr int K = KC * 32;           // K in shorts
    constexpr int CPR = KC * 4;          // 16B chunks per row
    constexpr int LOGCPR = (KC == 4) ? 4 : 5;
    constexpr int LPL = KC / 4;          // staging chunks per lane (1 or 2)
    __shared__ ushort abuf[2][16 * K];   // double-buffered strip (2x 4/8 KB)

    int tid = threadIdx.x;
    int lane = tid & 63;
    int w = tid >> 6;
    int cl = lane & 15, q = lane >> 4;
    int grp = blockIdx.x & ((1 << LOGNG) - 1);
    int s0 = blockIdx.x >> LOGNG;
    int TT = gridDim.x >> LOGNG;         // strip stride
    int colBase = grp * (4 * 16 * NT) + w * (16 * NT);
    int chBase = w * (16 * KC);          // this wave's staging chunk range

    // B fragments: loaded once (weights L2-resident)
    bf16x8 bf[NT][KC];
    #pragma unroll
    for (int nt = 0; nt < NT; nt++) {
        const ushort* bp = BT + (long)(colBase + nt * 16 + cl) * K + q * 8;
        #pragma unroll
        for (int kc = 0; kc < KC; kc++)
            bf[nt][kc] = *(const bf16x8*)(bp + kc * 32);
    }

    // BNIN: per-lane scale/shift for the 8 channels this lane stages
    // (chunk col c = (chBase+u*64+lane)&(CPR-1) is identical for all u since 64%CPR==0 or CPR==16)
    float sc8[8], sh8[8];
    if (BNIN) {
        int cb = ((chBase + lane) & (CPR - 1)) * 8;
        #pragma unroll
        for (int e = 0; e < 8; e++) {
            float mean = isums[cb + e] * invM;
            float var = isqs[cb + e] * invM - mean * mean;
            float s = igam[cb + e] * rsqrtf(var + BN_EPS);
            sc8[e] = s;
            sh8[e] = ibet[cb + e] - mean * s;
        }
    }

    float ssum[NT], ssq[NT];
    #pragma unroll
    for (int nt = 0; nt < NT; nt++) { ssum[nt] = 0.f; ssq[nt] = 0.f; }

    auto stage_load = [&](us8 (&stg)[LPL], int strip) {
        const ushort* As = A + (long)strip * 16 * K;
        #pragma unroll
        for (int u = 0; u < LPL; u++)
            stg[u] = *(const us8*)(As + (chBase + u * 64 + lane) * 8);
    };
    auto stage_write = [&](int buf, us8 (&stg)[LPL]) {
        #pragma unroll
        for (int u = 0; u < LPL; u++) {
            int ch = chBase + u * 64 + lane;
            int r = ch >> LOGCPR;
            int c = ch & (CPR - 1);
            us8 v = stg[u];
            if (BNIN) {
                us8 o;
                #pragma unroll
                for (int e = 0; e < 8; e++) {
                    float f = bf2f(v[e]) * sc8[e] + sh8[e];
                    f = (f > 0.f) ? f : f * negSlope;
                    o[e] = f2bf(f);
                }
                v = o;
            }
            *(us8*)(abuf[buf] + (((r << LOGCPR) + (c ^ (r & 7))) * 8)) = v;
        }
    };

    us8 stgA[LPL], stgB[LPL];
    int s = s0;
    // prologue: abuf[0] <- s0; stgB <- s0+TT; stgA <- s0+2TT (in flight)
    stage_load(stgA, s);
    if (s + TT < mStrips) stage_load(stgB, s + TT);
    stage_write(0, stgA);
    if (s + 2 * TT < mStrips) stage_load(stgA, s + 2 * TT);
    __syncthreads();
    int cur = 0;

    // STEP: af-reads first (lets MFMA wait only on reads), then ds_write next buf,
    // then issue depth-2 load, then MFMA + stores, one barrier.
#define GEMM_STEP(STG)                                                                  \
    {                                                                                   \
        bf16x8 af[KC];                                                                  \
        _Pragma("unroll")                                                               \
        for (int kc = 0; kc < KC; kc++)                                                 \
            af[kc] = *(const bf16x8*)(abuf[cur] +                                       \
                     (((cl << LOGCPR) + ((kc * 4 + q) ^ (cl & 7))) * 8));               \
        if (s + TT < mStrips) stage_write(cur ^ 1, STG);                                \
        if (s + 3 * TT < mStrips) stage_load(STG, s + 3 * TT);                          \
        f32x4 acc[NT] = {};                                                             \
        _Pragma("unroll")                                                               \
        for (int kc = 0; kc < KC; kc++)                                                 \
            _Pragma("unroll")                                                           \
            for (int nt = 0; nt < NT; nt++)                                             \
                acc[nt] = __builtin_amdgcn_mfma_f32_16x16x32_bf16(af[kc], bf[nt][kc],   \
                                                                  acc[nt], 0, 0, 0);    \
        int rowBase = s * 16;                                                           \
        _Pragma("unroll")                                                               \
        for (int nt = 0; nt < NT; nt++) {                                               \
            _Pragma("unroll")                                                           \
            for (int r = 0; r < 4; r++) {                                               \
                float v = acc[nt][r];                                                   \
                long row = rowBase + q * 4 + r;                                         \
                C[row * N + colBase + nt * 16 + cl] = f2bf(v);                          \
                if (STATS) { ssum[nt] += v; ssq[nt] += v * v; }                         \
            }                                                                           \
        }                                                                               \
        __syncthreads();                                                                \
        s += TT; cur ^= 1;                                                              \
    }

    while (true) {
        GEMM_STEP(stgB);
        if (s >= mStrips) break;
        GEMM_STEP(stgA);
        if (s >= mStrips) break;
    }
#undef GEMM_STEP

    if (STATS) {
        #pragma unroll
        for (int nt = 0; nt < NT; nt++) {
            ssum[nt] += __shfl_xor(ssum[nt], 16, 64);
            ssum[nt] += __shfl_xor(ssum[nt], 32, 64);
            ssq[nt]  += __shfl_xor(ssq[nt], 16, 64);
            ssq[nt]  += __shfl_xor(ssq[nt], 32, 64);
        }
        if (q == 0) {
            #pragma unroll
            for (int nt = 0; nt < NT; nt++) {
                atomicAdd(&gsums[colBase + nt * 16 + cl], ssum[nt]);
                atomicAdd(&gsqs[colBase + nt * 16 + cl], ssq[nt]);
            }
        }
    }
}

// ======== fused setup: convert nodes -> bf16, transpose weights, zero stats + degi/cursor ========
__global__ __launch_bounds__(256) void setup_all(
    const float* __restrict__ nodes, ushort* __restrict__ Xbf, int nConv4, int nbConv,
    const float* __restrict__ W0, const float* __restrict__ W1,
    const float* __restrict__ W2, const float* __restrict__ W3,
    const float* __restrict__ W4, const float* __restrict__ W5,
    ushort* __restrict__ WT,
    int* __restrict__ zeroInts, int nZero4, int nbZero,
    float* __restrict__ stats)
{
    int b = blockIdx.x;
    int tid = threadIdx.x;
    if (b < nbConv) {
        int t = b * 256 + tid;
        if (t < nConv4) {
            float4 v = *(const float4*)&nodes[(long)t * 4];
            ushort4 o; o.x = f2bf(v.x); o.y = f2bf(v.y); o.z = f2bf(v.z); o.w = f2bf(v.w);
            *(ushort4*)&Xbf[(long)t * 4] = o;
        }
        return;
    }
    b -= nbConv;
    if (b < 768) {
        int seg = b >> 7;
        const float* W; int logK, dstBase, stride, kOff;
        switch (seg) {
            case 0: W = W0; logK = 7; dstBase = 0;      stride = 128; kOff = 0;   break;
            case 1: W = W1; logK = 8; dstBase = 32768;  stride = 256; kOff = 0;   break;
            case 2: W = W2; logK = 7; dstBase = 65536;  stride = 256; kOff = 0;   break;
            case 3: W = W3; logK = 7; dstBase = 65536;  stride = 256; kOff = 128; break;
            case 4: W = W4; logK = 8; dstBase = 131072; stride = 256; kOff = 0;   break;
            default:W = W5; logK = 8; dstBase = 163840; stride = 256; kOff = 0;   break;
        }
        int t = (b & 127) * 256 + tid;
        int N = 32768 >> logK;
        int k = t & ((1 << logK) - 1);
        int n = t >> logK;
        WT[(long)dstBase + (long)n * stride + kOff + k] = f2bf(W[(long)k * N + n]);
        return;
    }
    b -= 768;
    if (b < nbZero) {
        int t = b * 256 + tid;
        if (t < nZero4) *(int4*)&zeroInts[(long)t * 4] = make_int4(0, 0, 0, 0);
        return;
    }
    b -= nbZero;
    int t = b * 256 + tid;
    if (t < 512) *(float4*)&stats[(long)t * 4] = make_float4(0, 0, 0, 0);
}

// ======== BN params folded into activation: bf16 -> bf16, 16B/lane, fixed channels/thread ========
template<int LOGN>
__global__ __launch_bounds__(256) void bnact_bf16(
    const ushort* __restrict__ X,
    const float* __restrict__ sums, const float* __restrict__ sqs,
    const float* __restrict__ gamma, const float* __restrict__ beta, float invM,
    ushort* __restrict__ O, int nRows, int outStride, float negSlope)
{
    constexpr int NCH = 1 << LOGN;
    __shared__ float ssc[NCH], ssh[NCH];
    int tid = threadIdx.x;
    if (tid < NCH) {
        float mean = sums[tid] * invM;
        float var = sqs[tid] * invM - mean * mean;
        float sc = gamma[tid] * rsqrtf(var + BN_EPS);
        ssc[tid] = sc;
        ssh[tid] = beta[tid] - mean * sc;
    }
    __syncthreads();
    int cb = (tid * 8) & (NCH - 1);
    float4 sA = *(const float4*)&ssc[cb];
    float4 sB = *(const float4*)&ssc[cb + 4];
    float4 hA = *(const float4*)&ssh[cb];
    float4 hB = *(const float4*)&ssh[cb + 4];
    const int rpb = (256 * 8) >> LOGN;            // rows per block pass
    int r0 = blockIdx.x * rpb + ((tid * 8) >> LOGN);
    int rstride = gridDim.x * rpb;
    for (int row = r0; row < nRows; row += rstride) {
        us8 v = *(const us8*)&X[(long)row * NCH + cb];
        float f0 = bf2f(v[0]) * sA.x + hA.x; f0 = (f0 > 0.f) ? f0 : f0 * negSlope;
        float f1 = bf2f(v[1]) * sA.y + hA.y; f1 = (f1 > 0.f) ? f1 : f1 * negSlope;
        float f2 = bf2f(v[2]) * sA.z + hA.z; f2 = (f2 > 0.f) ? f2 : f2 * negSlope;
        float f3 = bf2f(v[3]) * sA.w + hA.w; f3 = (f3 > 0.f) ? f3 : f3 * negSlope;
        float f4 = bf2f(v[4]) * sB.x + hB.x; f4 = (f4 > 0.f) ? f4 : f4 * negSlope;
        float f5 = bf2f(v[5]) * sB.y + hB.y; f5 = (f5 > 0.f) ? f5 : f5 * negSlope;
        float f6 = bf2f(v[6]) * sB.z + hB.z; f6 = (f6 > 0.f) ? f6 : f6 * negSlope;
        float f7 = bf2f(v[7]) * sB.w + hB.w; f7 = (f7 > 0.f) ? f7 : f7 * negSlope;
        us8 o;
        o[0] = f2bf(f0); o[1] = f2bf(f1); o[2] = f2bf(f2); o[3] = f2bf(f3);
        o[4] = f2bf(f4); o[5] = f2bf(f5); o[6] = f2bf(f6); o[7] = f2bf(f7);
        *(us8*)&O[(long)row * outStride + cb] = o;
    }
}

// ======== BN params folded, fp32 in-place (final output, 128 ch) ========
__global__ __launch_bounds__(256) void bnact_f32(
    float* __restrict__ X,
    const float* __restrict__ sums, const float* __restrict__ sqs,
    const float* __restrict__ gamma, const float* __restrict__ beta, float invM,
    int nRows, float negSlope)
{
    __shared__ float ssc[128], ssh[128];
    int tid = threadIdx.x;
    if (tid < 128) {
        float mean = sums[tid] * invM;
        float var = sqs[tid] * invM - mean * mean;
        float sc = gamma[tid] * rsqrtf(var + BN_EPS);
        ssc[tid] = sc;
        ssh[tid] = beta[tid] - mean * sc;
    }
    __syncthreads();
    int cb = (tid * 4) & 127;
    float4 sc = *(const float4*)&ssc[cb];
    float4 sh = *(const float4*)&ssh[cb];
    int r0 = blockIdx.x * 8 + ((tid * 4) >> 7);
    int rstride = gridDim.x * 8;
    for (int row = r0; row < nRows; row += rstride) {
        float4 v = *(const float4*)&X[(long)row * 128 + cb];
        float a = v.x * sc.x + sh.x; a = (a > 0.f) ? a : a * negSlope;
        float b = v.y * sc.y + sh.y; b = (b > 0.f) ? b : b * negSlope;
        float d = v.z * sc.z + sh.z; d = (d > 0.f) ? d : d * negSlope;
        float e = v.w * sc.w + sh.w; e = (e > 0.f) ? e : e * negSlope;
        *(float4*)&X[(long)row * 128 + cb] = make_float4(a, b, d, e);
    }
}

// ======== column stats for final output (128 cols, register accum) ========
__global__ __launch_bounds__(256) void colstats128(
    const float* __restrict__ X, float* __restrict__ sums, float* __restrict__ sqs, int M)
{
    __shared__ float ss[128], sq[128];
    int tid = threadIdx.x;
    if (tid < 128) { ss[tid] = 0.f; sq[tid] = 0.f; }
    __syncthreads();
    int cg = tid & 31;
    int worker = (blockIdx.x << 3) | (tid >> 5);
    int totalW = gridDim.x << 3;
    float4 s4 = make_float4(0, 0, 0, 0), q4 = make_float4(0, 0, 0, 0);
    for (int r = worker; r < M; r += totalW) {
        float4 v = *(const float4*)&X[(long)r * 128 + cg * 4];
        s4.x += v.x; s4.y += v.y; s4.z += v.z; s4.w += v.w;
        q4.x += v.x * v.x; q4.y += v.y * v.y; q4.z += v.z * v.z; q4.w += v.w * v.w;
    }
    atomicAdd(&ss[cg * 4 + 0], s4.x); atomicAdd(&sq[cg * 4 + 0], q4.x);
    atomicAdd(&ss[cg * 4 + 1], s4.y); atomicAdd(&sq[cg * 4 + 1], q4.y);
    atomicAdd(&ss[cg * 4 + 2], s4.z); atomicAdd(&sq[cg * 4 + 2], q4.z);
    atomicAdd(&ss[cg * 4 + 3], s4.w); atomicAdd(&sq[cg * 4 + 3], q4.w);
    __syncthreads();
    if (tid < 128) { atomicAdd(&sums[tid], ss[tid]); atomicAdd(&sqs[tid], sq[tid]); }
}

// ======== CSR build ========
__global__ void degcount_kernel(const int* __restrict__ dst, int* __restrict__ degi, int E)
{
    int i = blockIdx.x * blockDim.x + threadIdx.x;
    if (i < E) atomicAdd(&degi[dst[i]], 1);
}

__global__ __launch_bounds__(256) void scan_block_sums(const int* __restrict__ degi,
                                                       int* __restrict__ partial, int n)
{
    __shared__ int s[256];
    int i = blockIdx.x * 256 + threadIdx.x;
    s[threadIdx.x] = (i < n) ? degi[i] : 0;
    __syncthreads();
    for (int off = 128; off > 0; off >>= 1) {
        if (threadIdx.x < off) s[threadIdx.x] += s[threadIdx.x + off];
        __syncthreads();
    }
    if (threadIdx.x == 0) partial[blockIdx.x] = s[0];
}

// scan_final also reduces the block-offset from raw per-block sums (scan_partials folded in)
__global__ __launch_bounds__(256) void scan_final(const int* __restrict__ degi,
                                                  const int* __restrict__ partial,
                                                  int* __restrict__ rowstart, int n, int nb)
{
    __shared__ int s[256];
    __shared__ int ps[256];
    int tid = threadIdx.x;
    ps[tid] = (tid < nb && tid < (int)blockIdx.x) ? partial[tid] : 0;
    __syncthreads();
    for (int off = 128; off > 0; off >>= 1) {
        if (tid < off) ps[tid] += ps[tid + off];
        __syncthreads();
    }
    int offset = ps[0];
    int i = blockIdx.x * 256 + tid;
    int v = (i < n) ? degi[i] : 0;
    s[tid] = v;
    __syncthreads();
    for (int off = 1; off < 256; off <<= 1) {
        int t = (tid >= off) ? s[tid - off] : 0;
        __syncthreads();
        s[tid] += t;
        __syncthreads();
    }
    if (i < n) rowstart[i] = offset + s[tid] - v;
}

__global__ void fillcsr_kernel(const int* __restrict__ src, const int* __restrict__ dst,
                               const int* __restrict__ rowstart, int* __restrict__ cursor,
                               int* __restrict__ csr, int E)
{
    int i = blockIdx.x * blockDim.x + threadIdx.x;
    if (i < E) {
        int d = dst[i];
        int p = atomicAdd(&cursor[d], 1);
        csr[rowstart[d] + p] = src[i];
    }
}

// ======== gather16: 16-lane group per edge, dwordx4 per lane (4 rows / wave-load) ========
__device__ __forceinline__ void acc8(float acc[8], us8 v) {
    #pragma unroll
    for (int e = 0; e < 8; e++) acc[e] += bf2f(v[e]);
}

// mean-gather bf16 -> bf16 (in: rows of X, 256-col stride, first 128 cols; out: O + wv*256)
__global__ __launch_bounds__(256) void gather16_bf(
    const ushort* __restrict__ X, const int* __restrict__ rowstart,
    const int* __restrict__ degi, const int* __restrict__ csr,
    ushort* __restrict__ O, int nN)
{
    int wv = (blockIdx.x * blockDim.x + threadIdx.x) >> 6;
    int lane = threadIdx.x & 63;
    if (wv >= nN) return;
    int g = lane >> 4;        // edge slot 0..3
    int sc = lane & 15;       // 16-B chunk of row
    int start = rowstart[wv], d = degi[wv];
    const ushort* Xc = X + sc * 8;
    float acc[8] = {};
    if (d > 0) {
        int dm = (d < 64) ? d : 64;
        int idx_l = csr[start + ((lane < dm) ? lane : (dm - 1))];
        int j = 0;
        for (; j + 8 <= dm; j += 8) {
            int i0 = __shfl(idx_l, j + g, 64);
            int i1 = __shfl(idx_l, j + 4 + g, 64);
            us8 v0 = *(const us8*)(Xc + (long)i0 * 256);
            us8 v1 = *(const us8*)(Xc + (long)i1 * 256);
            acc8(acc, v0);
            acc8(acc, v1);
        }
        if (j + 4 <= dm) {
            int i0 = __shfl(idx_l, j + g, 64);
            us8 v0 = *(const us8*)(Xc + (long)i0 * 256);
            acc8(acc, v0);
            j += 4;
        }
        int rem = dm - j;
        if (rem > 0) {
            int sl = j + ((g < rem) ? g : (rem - 1));
            int i0 = __shfl(idx_l, sl, 64);
            if (g < rem) {
                us8 v0 = *(const us8*)(Xc + (long)i0 * 256);
                acc8(acc, v0);
            }
        }
        for (int jj = 64; jj < d; jj += 4) {     // rare: degree > 64
            if (jj + g < d) {
                int i0 = csr[start + jj + g];
                us8 v0 = *(const us8*)(Xc + (long)i0 * 256);
                acc8(acc, v0);
            }
        }
    }
    #pragma unroll
    for (int e = 0; e < 8; e++) {
        acc[e] += __shfl_xor(acc[e], 16, 64);
        acc[e] += __shfl_xor(acc[e], 32, 64);
    }
    if (g == 0) {
        float inv = 1.f / fmaxf((float)d, 1.f);
        us8 o;
        #pragma unroll
        for (int e = 0; e < 8; e++) o[e] = f2bf(acc[e] * inv);
        *(us8*)(O + (long)wv * 256 + sc * 8) = o;
    }
}

// fused gather2: out = mean(Z[src, 0:128]) + Z[dst, 128:256]  (fp32 out, 128 cols)
__global__ __launch_bounds__(256) void gather16_fuse(
    const ushort* __restrict__ Z, const int* __restrict__ rowstart,
    const int* __restrict__ degi, const int* __restrict__ csr,
    float* __restrict__ O, int nN)
{
    int wv = (blockIdx.x * blockDim.x + threadIdx.x) >> 6;
    int lane = threadIdx.x & 63;
    if (wv >= nN) return;
    int g = lane >> 4;
    int sc = lane & 15;
    int start = rowstart[wv], d = degi[wv];
    const ushort* Zc = Z + sc * 8;
    us8 selfv = *(const us8*)(Zc + (long)wv * 256 + 128);   // independent, issued early
    float acc[8] = {};
    if (d > 0) {
        int dm = (d < 64) ? d : 64;
        int idx_l = csr[start + ((lane < dm) ? lane : (dm - 1))];
        int j = 0;
        for (; j + 8 <= dm; j += 8) {
            int i0 = __shfl(idx_l, j + g, 64);
            int i1 = __shfl(idx_l, j + 4 + g, 64);
            us8 v0 = *(const us8*)(Zc + (long)i0 * 256);
            us8 v1 = *(const us8*)(Zc + (long)i1 * 256);
            acc8(acc, v0);
            acc8(acc, v1);
        }
        if (j + 4 <= dm) {
            int i0 = __shfl(idx_l, j + g, 64);
            us8 v0 = *(const us8*)(Zc + (long)i0 * 256);
            acc8(acc, v0);
            j += 4;
        }
        int rem = dm - j;
        if (rem > 0) {
            int sl = j + ((g < rem) ? g : (rem - 1));
            int i0 = __shfl(idx_l, sl, 64);
            if (g < rem) {
                us8 v0 = *(const us8*)(Zc + (long)i0 * 256);
                acc8(acc, v0);
            }
        }
        for (int jj = 64; jj < d; jj += 4) {
            if (jj + g < d) {
                int i0 = csr[start + jj + g];
                us8 v0 = *(const us8*)(Zc + (long)i0 * 256);
                acc8(acc, v0);
            }
        }
    }
    #pragma unroll
    for (int e = 0; e < 8; e++) {
        acc[e] += __shfl_xor(acc[e], 16, 64);
        acc[e] += __shfl_xor(acc[e], 32, 64);
    }
    if (g == 0) {
        float inv = 1.f / fmaxf((float)d, 1.f);
        float r[8];
        #pragma unroll
        for (int e = 0; e < 8; e++) r[e] = acc[e] * inv + bf2f(selfv[e]);
        float* op = O + (long)wv * 128 + sc * 8;
        *(float4*)op = make_float4(r[0], r[1], r[2], r[3]);
        *(float4*)(op + 4) = make_float4(r[4], r[5], r[6], r[7]);
    }
}

extern "C" void kernel_launch(void* const* d_in, const int* in_sizes, int n_in,
                              void* d_out, int out_size, void* d_ws, size_t ws_size,
                              hipStream_t stream)
{
    const float* nodes = (const float*)d_in[0];
    const int*   src   = (const int*)d_in[1];
    const int*   dst   = (const int*)d_in[2];
    const float* Wf1   = (const float*)d_in[3];
    const float* gf1   = (const float*)d_in[5];
    const float* bef1  = (const float*)d_in[6];
    const float* Wf2   = (const float*)d_in[7];
    const float* gf2   = (const float*)d_in[9];
    const float* bef2  = (const float*)d_in[10];
    const float* Ws1   = (const float*)d_in[11];
    const float* Wn1   = (const float*)d_in[12];
    const float* gs1   = (const float*)d_in[14];
    const float* bs1   = (const float*)d_in[15];
    const float* Ws2   = (const float*)d_in[16];
    const float* Wn2   = (const float*)d_in[17];
    const float* gs2   = (const float*)d_in[19];
    const float* bs2   = (const float*)d_in[20];
    // pre-BN biases (bf1,bf2,b1,b2) cancel under BatchNorm -> skipped

    int nN = in_sizes[0] / DIN;   // 50000
    int nE = in_sizes[1];         // 600000
    float* out = (float*)d_out;
    int mStrips = nN / 16;        // 3125 (exact)
    float invM = 1.0f / nN;

    // ---- workspace (identical layout to passing version) ----
    ushort* PRE = (ushort*)d_ws;                      // nN*256 bf16 raw GEMM out
    ushort* BF1 = PRE + (size_t)nN * 256;             // nN*256 bf16 (Xn / FF2 raw)
    ushort* BF2 = BF1 + (size_t)nN * 256;             // nN*256 bf16 ([h|agg] / Z)
    float* stats = (float*)(BF2 + (size_t)nN * 256);  // 2048 floats, 4 layer-regions
    float* scale = stats + 2048;                      // 256 (unused, kept for layout)
    float* shift = scale + 256;                       // 256 (unused, kept for layout)
    ushort* WT   = (ushort*)(shift + 256);            // 196608 shorts
    int* degi     = (int*)(WT + 196608);              // nN
    int* cursor   = degi + nN;                        // nN (adjacent: zeroed together)
    int* rowstart = cursor + nN;                      // nN
    int* partial  = rowstart + nN;                    // 256
    int* csr      = partial + 256;                    // nE

    ushort* Wf1T = WT;
    ushort* Wf2T = WT + 32768;
    ushort* Wc1T = WT + 65536;
    ushort* Wc2T = WT + 131072;

    dim3 blk(256);
    auto cdiv = [](int a, int b) { return (a + b - 1) / b; };
    int nScanBlocks = cdiv(nN, 256);                  // 196 (must be <= 256)

    // ---- fused setup: convert + weight transpose + zero stats/degi/cursor ----
    int nConv4 = nN * DIN / 4;
    int nbConv = cdiv(nConv4, 256);
    int nZero4 = (2 * nN) / 4;
    int nbZero = cdiv(nZero4, 256);
    setup_all<<<dim3(nbConv + 768 + nbZero + 2), blk, 0, stream>>>(
        nodes, BF1, nConv4, nbConv,
        Wf1, Wf2, Ws1, Wn1, Wn2, Ws2, WT,
        degi, nZero4, nbZero, stats);

    // ---- CSR build ----
    degcount_kernel<<<dim3(cdiv(nE, 256)), blk, 0, stream>>>(dst, degi, nE);
    scan_block_sums<<<dim3(nScanBlocks), blk, 0, stream>>>(degi, partial, nN);
    scan_final<<<dim3(nScanBlocks), blk, 0, stream>>>(degi, partial, rowstart, nN, nScanBlocks);
    fillcsr_kernel<<<dim3(cdiv(nE, 256)), blk, 0, stream>>>(src, dst, rowstart, cursor, csr, nE);

    // ---- FF1: PRE = Xn @ Wf1T (K=128, N=256, stats->L0), plain staging ----
    gemm_lds<4, 4, 0, 1, 0><<<dim3(512), blk, 0, stream>>>(
        BF1, Wf1T, PRE, mStrips, 256, stats, stats + 256,
        nullptr, nullptr, nullptr, nullptr, 0.f, 0.f);

    // ---- FF2: BF1 = act(BN_L0(PRE)) @ Wf2T (BN+ReLU fused into staging; K=256, N=128, stats->L1) ----
    gemm_lds<8, 2, 0, 1, 1><<<dim3(512), blk, 0, stream>>>(
        PRE, Wf2T, BF1, mStrips, 128, stats + 512, stats + 768,
        stats, stats + 256, gf1, bef1, invM, 0.0f);

    // ---- BN_L1+ReLU: BF1(compact 128) -> BF2[:,0:128] (2 consumers: gather + SAGE1) ----
    bnact_bf16<7><<<dim3(2048), blk, 0, stream>>>(BF1, stats + 512, stats + 768, gf2, bef2, invM,
                                                  BF2, nN, 256, 0.0f);

    // ---- gather1: BF2[:,128:256] = mean-gather(BF2[:,0:128]) ----
    gather16_bf<<<dim3(cdiv(nN * 64, 256)), blk, 0, stream>>>(BF2, rowstart, degi, csr, BF2 + 128, nN);

    // ---- SAGE1: PRE = [h|agg] @ [Ws1;Wn1] (K=256, N=256, stats->L2), plain staging ----
    gemm_lds<8, 4, 0, 1, 0><<<dim3(512), blk, 0, stream>>>(
        BF2, Wc1T, PRE, mStrips, 256, stats + 1024, stats + 1280,
        nullptr, nullptr, nullptr, nullptr, 0.f, 0.f);

    // ---- SAGE2: BF2 = act(BN_L2(PRE)) @ [Wn2|Ws2] (BN+LReLU fused into staging;
    //      K=256, N=256, NT=2 with 2 col-groups to bound VGPR, no stats) ----
    gemm_lds<8, 2, 1, 0, 1><<<dim3(512), blk, 0, stream>>>(
        PRE, Wc2T, BF2, mStrips, 256, nullptr, nullptr,
        stats + 1024, stats + 1280, gs1, bs1, invM, 0.01f);

    // ---- gather_fuse -> out(fp32) ----
    gather16_fuse<<<dim3(cdiv(nN * 64, 256)), blk, 0, stream>>>(BF2, rowstart, degi, csr, out, nN);

    // ---- final: colstats -> fused BN+LReLU on out ----
    colstats128<<<dim3(120), blk, 0, stream>>>(out, stats + 1536, stats + 1792, nN);
    bnact_f32<<<dim3(2048), blk, 0, stream>>>(out, stats + 1536, stats + 1792, gs2, bs2, invM,
                                              nN, 0.01f);
}

// Round 8
// 351.075 us; speedup vs baseline: 1.1591x; 1.0127x over previous
//
#include <hip/hip_runtime.h>

#define DIN 128
#define BN_EPS 1e-5f

typedef __attribute__((ext_vector_type(8))) short bf16x8;
typedef __attribute__((ext_vector_type(8))) unsigned short us8;
typedef __attribute__((ext_vector_type(4))) float f32x4;

__device__ __forceinline__ ushort f2bf(float f) {
    unsigned u = __float_as_uint(f);
    u += 0x7fffu + ((u >> 16) & 1u);
    return (ushort)(u >> 16);
}
__device__ __forceinline__ float bf2f(ushort h) {
    return __uint_as_float(((unsigned)h) << 16);
}

// ======== LDS-shared streaming GEMM v3: C[M,N](bf16) = A[M,K](bf16) @ BT[N,K]^T ========
// R7 base (block-shared A strip, double-buffered LDS, depth-2 prefetch, 1 barrier/strip,
// BN folded into staging) plus BNIN=2: dual-source staging for SAGE1's A=[h|agg] --
// chunk-col c<16 lanes read raw BF1 applying BN_L1+ReLU (bit-identical to the old
// bnact pass), c>=16 lanes read AGG with identity params (agg>=0 so ReLU is a no-op).
template<int KC, int NT, int LOGNG, int STATS, int BNIN>
__global__ __launch_bounds__(256) void gemm_lds(
    const ushort* __restrict__ A, const ushort* __restrict__ BT,
    ushort* __restrict__ C, int mStrips, int N,
    float* __restrict__ gsums, float* __restrict__ gsqs,
    const float* __restrict__ isums, const float* __restrict__ isqs,
    const float* __restrict__ igam, const float* __restrict__ ibet,
    float invM, float negSlope,
    const ushort* __restrict__ A2)
{
    constexpr int K = KC * 32;           // K in shorts
    constexpr int CPR = KC * 4;          // 16B chunks per row
    constexpr int LOGCPR = (KC == 4) ? 4 : 5;
    constexpr int LPL = KC / 4;          // staging chunks per lane (1 or 2)
    __shared__ ushort abuf[2][16 * K];   // double-buffered strip (2x 4/8 KB)

    int tid = threadIdx.x;
    int lane = tid & 63;
    int w = tid >> 6;
    int cl = lane & 15, q = lane >> 4;
    int grp = blockIdx.x & ((1 << LOGNG) - 1);
    int s0 = blockIdx.x >> LOGNG;
    int TT = gridDim.x >> LOGNG;         // strip stride
    int colBase = grp * (4 * 16 * NT) + w * (16 * NT);
    int chBase = w * (16 * KC);          // this wave's staging chunk range

    // B fragments: loaded once (weights L2-resident)
    bf16x8 bf[NT][KC];
    #pragma unroll
    for (int nt = 0; nt < NT; nt++) {
        const ushort* bp = BT + (long)(colBase + nt * 16 + cl) * K + q * 8;
        #pragma unroll
        for (int kc = 0; kc < KC; kc++)
            bf[nt][kc] = *(const bf16x8*)(bp + kc * 32);
    }

    // BN-in-staging params: the lane's staging chunks share one K-column
    float sc8[8], sh8[8];
    const ushort* dsrc = A;              // BNIN==2: per-lane source base
    int dcol = 0;
    if (BNIN == 1) {
        int cb = ((chBase + lane) & (CPR - 1)) * 8;
        #pragma unroll
        for (int e = 0; e < 8; e++) {
            float mean = isums[cb + e] * invM;
            float var = isqs[cb + e] * invM - mean * mean;
            float s = igam[cb + e] * rsqrtf(var + BN_EPS);
            sc8[e] = s;
            sh8[e] = ibet[cb + e] - mean * s;
        }
    } else if (BNIN == 2) {
        int c = (chBase + lane) & (CPR - 1);
        dsrc = (c < 16) ? A : A2;
        dcol = (c & 15) * 8;
        if (c < 16) {
            int cb = c * 8;
            #pragma unroll
            for (int e = 0; e < 8; e++) {
                float mean = isums[cb + e] * invM;
                float var = isqs[cb + e] * invM - mean * mean;
                float s = igam[cb + e] * rsqrtf(var + BN_EPS);
                sc8[e] = s;
                sh8[e] = ibet[cb + e] - mean * s;
            }
        } else {
            #pragma unroll
            for (int e = 0; e < 8; e++) { sc8[e] = 1.0f; sh8[e] = 0.0f; }
        }
    }

    float ssum[NT], ssq[NT];
    #pragma unroll
    for (int nt = 0; nt < NT; nt++) { ssum[nt] = 0.f; ssq[nt] = 0.f; }

    auto stage_load = [&](us8 (&stg)[LPL], int strip) {
        if (BNIN == 2) {
            #pragma unroll
            for (int u = 0; u < LPL; u++) {
                int r = (chBase + u * 64 + lane) >> LOGCPR;
                stg[u] = *(const us8*)(dsrc + ((long)(strip * 16 + r)) * 128 + dcol);
            }
        } else {
            const ushort* As = A + (long)strip * 16 * K;
            #pragma unroll
            for (int u = 0; u < LPL; u++)
                stg[u] = *(const us8*)(As + (chBase + u * 64 + lane) * 8);
        }
    };
    auto stage_write = [&](int buf, us8 (&stg)[LPL]) {
        #pragma unroll
        for (int u = 0; u < LPL; u++) {
            int ch = chBase + u * 64 + lane;
            int r = ch >> LOGCPR;
            int c = ch & (CPR - 1);
            us8 v = stg[u];
            if (BNIN != 0) {
                us8 o;
                #pragma unroll
                for (int e = 0; e < 8; e++) {
                    float f = bf2f(v[e]) * sc8[e] + sh8[e];
                    f = (f > 0.f) ? f : f * negSlope;
                    o[e] = f2bf(f);
                }
                v = o;
            }
            *(us8*)(abuf[buf] + (((r << LOGCPR) + (c ^ (r & 7))) * 8)) = v;
        }
    };

    us8 stgA[LPL], stgB[LPL];
    int s = s0;
    // prologue: abuf[0] <- s0; stgB <- s0+TT; stgA <- s0+2TT (in flight)
    stage_load(stgA, s);
    if (s + TT < mStrips) stage_load(stgB, s + TT);
    stage_write(0, stgA);
    if (s + 2 * TT < mStrips) stage_load(stgA, s + 2 * TT);
    __syncthreads();
    int cur = 0;

#define GEMM_STEP(STG)                                                                  \
    {                                                                                   \
        bf16x8 af[KC];                                                                  \
        _Pragma("unroll")                                                               \
        for (int kc = 0; kc < KC; kc++)                                                 \
            af[kc] = *(const bf16x8*)(abuf[cur] +                                       \
                     (((cl << LOGCPR) + ((kc * 4 + q) ^ (cl & 7))) * 8));               \
        if (s + TT < mStrips) stage_write(cur ^ 1, STG);                                \
        if (s + 3 * TT < mStrips) stage_load(STG, s + 3 * TT);                          \
        f32x4 acc[NT] = {};                                                             \
        _Pragma("unroll")                                                               \
        for (int kc = 0; kc < KC; kc++)                                                 \
            _Pragma("unroll")                                                           \
            for (int nt = 0; nt < NT; nt++)                                             \
                acc[nt] = __builtin_amdgcn_mfma_f32_16x16x32_bf16(af[kc], bf[nt][kc],   \
                                                                  acc[nt], 0, 0, 0);    \
        int rowBase = s * 16;                                                           \
        _Pragma("unroll")                                                               \
        for (int nt = 0; nt < NT; nt++) {                                               \
            _Pragma("unroll")                                                           \
            for (int r = 0; r < 4; r++) {                                               \
                float v = acc[nt][r];                                                   \
                long row = rowBase + q * 4 + r;                                         \
                C[row * N + colBase + nt * 16 + cl] = f2bf(v);                          \
                if (STATS) { ssum[nt] += v; ssq[nt] += v * v; }                         \
            }                                                                           \
        }                                                                               \
        __syncthreads();                                                                \
        s += TT; cur ^= 1;                                                              \
    }

    while (true) {
        GEMM_STEP(stgB);
        if (s >= mStrips) break;
        GEMM_STEP(stgA);
        if (s >= mStrips) break;
    }
#undef GEMM_STEP

    if (STATS) {
        #pragma unroll
        for (int nt = 0; nt < NT; nt++) {
            ssum[nt] += __shfl_xor(ssum[nt], 16, 64);
            ssum[nt] += __shfl_xor(ssum[nt], 32, 64);
            ssq[nt]  += __shfl_xor(ssq[nt], 16, 64);
            ssq[nt]  += __shfl_xor(ssq[nt], 32, 64);
        }
        if (q == 0) {
            #pragma unroll
            for (int nt = 0; nt < NT; nt++) {
                atomicAdd(&gsums[colBase + nt * 16 + cl], ssum[nt]);
                atomicAdd(&gsqs[colBase + nt * 16 + cl], ssq[nt]);
            }
        }
    }
}

// ======== fused setup: convert nodes -> bf16, transpose weights, zero stats + degi/cursor ========
__global__ __launch_bounds__(256) void setup_all(
    const float* __restrict__ nodes, ushort* __restrict__ Xbf, int nConv4, int nbConv,
    const float* __restrict__ W0, const float* __restrict__ W1,
    const float* __restrict__ W2, const float* __restrict__ W3,
    const float* __restrict__ W4, const float* __restrict__ W5,
    ushort* __restrict__ WT,
    int* __restrict__ zeroInts, int nZero4, int nbZero,
    float* __restrict__ stats)
{
    int b = blockIdx.x;
    int tid = threadIdx.x;
    if (b < nbConv) {
        int t = b * 256 + tid;
        if (t < nConv4) {
            float4 v = *(const float4*)&nodes[(long)t * 4];
            ushort4 o; o.x = f2bf(v.x); o.y = f2bf(v.y); o.z = f2bf(v.z); o.w = f2bf(v.w);
            *(ushort4*)&Xbf[(long)t * 4] = o;
        }
        return;
    }
    b -= nbConv;
    if (b < 768) {
        int seg = b >> 7;
        const float* W; int logK, dstBase, stride, kOff;
        switch (seg) {
            case 0: W = W0; logK = 7; dstBase = 0;      stride = 128; kOff = 0;   break;
            case 1: W = W1; logK = 8; dstBase = 32768;  stride = 256; kOff = 0;   break;
            case 2: W = W2; logK = 7; dstBase = 65536;  stride = 256; kOff = 0;   break;
            case 3: W = W3; logK = 7; dstBase = 65536;  stride = 256; kOff = 128; break;
            case 4: W = W4; logK = 8; dstBase = 131072; stride = 256; kOff = 0;   break;
            default:W = W5; logK = 8; dstBase = 163840; stride = 256; kOff = 0;   break;
        }
        int t = (b & 127) * 256 + tid;
        int N = 32768 >> logK;
        int k = t & ((1 << logK) - 1);
        int n = t >> logK;
        WT[(long)dstBase + (long)n * stride + kOff + k] = f2bf(W[(long)k * N + n]);
        return;
    }
    b -= 768;
    if (b < nbZero) {
        int t = b * 256 + tid;
        if (t < nZero4) *(int4*)&zeroInts[(long)t * 4] = make_int4(0, 0, 0, 0);
        return;
    }
    b -= nbZero;
    int t = b * 256 + tid;
    if (t < 512) *(float4*)&stats[(long)t * 4] = make_float4(0, 0, 0, 0);
}

// ======== BN params folded, fp32 in-place (final output, 128 ch) ========
__global__ __launch_bounds__(256) void bnact_f32(
    float* __restrict__ X,
    const float* __restrict__ sums, const float* __restrict__ sqs,
    const float* __restrict__ gamma, const float* __restrict__ beta, float invM,
    int nRows, float negSlope)
{
    __shared__ float ssc[128], ssh[128];
    int tid = threadIdx.x;
    if (tid < 128) {
        float mean = sums[tid] * invM;
        float var = sqs[tid] * invM - mean * mean;
        float sc = gamma[tid] * rsqrtf(var + BN_EPS);
        ssc[tid] = sc;
        ssh[tid] = beta[tid] - mean * sc;
    }
    __syncthreads();
    int cb = (tid * 4) & 127;
    float4 sc = *(const float4*)&ssc[cb];
    float4 sh = *(const float4*)&ssh[cb];
    int r0 = blockIdx.x * 8 + ((tid * 4) >> 7);
    int rstride = gridDim.x * 8;
    for (int row = r0; row < nRows; row += rstride) {
        float4 v = *(const float4*)&X[(long)row * 128 + cb];
        float a = v.x * sc.x + sh.x; a = (a > 0.f) ? a : a * negSlope;
        float b = v.y * sc.y + sh.y; b = (b > 0.f) ? b : b * negSlope;
        float d = v.z * sc.z + sh.z; d = (d > 0.f) ? d : d * negSlope;
        float e = v.w * sc.w + sh.w; e = (e > 0.f) ? e : e * negSlope;
        *(float4*)&X[(long)row * 128 + cb] = make_float4(a, b, d, e);
    }
}

// ======== column stats for final output (128 cols, register accum) ========
__global__ __launch_bounds__(256) void colstats128(
    const float* __restrict__ X, float* __restrict__ sums, float* __restrict__ sqs, int M)
{
    __shared__ float ss[128], sq[128];
    int tid = threadIdx.x;
    if (tid < 128) { ss[tid] = 0.f; sq[tid] = 0.f; }
    __syncthreads();
    int cg = tid & 31;
    int worker = (blockIdx.x << 3) | (tid >> 5);
    int totalW = gridDim.x << 3;
    float4 s4 = make_float4(0, 0, 0, 0), q4 = make_float4(0, 0, 0, 0);
    for (int r = worker; r < M; r += totalW) {
        float4 v = *(const float4*)&X[(long)r * 128 + cg * 4];
        s4.x += v.x; s4.y += v.y; s4.z += v.z; s4.w += v.w;
        q4.x += v.x * v.x; q4.y += v.y * v.y; q4.z += v.z * v.z; q4.w += v.w * v.w;
    }
    atomicAdd(&ss[cg * 4 + 0], s4.x); atomicAdd(&sq[cg * 4 + 0], q4.x);
    atomicAdd(&ss[cg * 4 + 1], s4.y); atomicAdd(&sq[cg * 4 + 1], q4.y);
    atomicAdd(&ss[cg * 4 + 2], s4.z); atomicAdd(&sq[cg * 4 + 2], q4.z);
    atomicAdd(&ss[cg * 4 + 3], s4.w); atomicAdd(&sq[cg * 4 + 3], q4.w);
    __syncthreads();
    if (tid < 128) { atomicAdd(&sums[tid], ss[tid]); atomicAdd(&sqs[tid], sq[tid]); }
}

// ======== CSR build ========
__global__ void degcount_kernel(const int* __restrict__ dst, int* __restrict__ degi, int E)
{
    int i = blockIdx.x * blockDim.x + threadIdx.x;
    if (i < E) atomicAdd(&degi[dst[i]], 1);
}

__global__ __launch_bounds__(256) void scan_block_sums(const int* __restrict__ degi,
                                                       int* __restrict__ partial, int n)
{
    __shared__ int s[256];
    int i = blockIdx.x * 256 + threadIdx.x;
    s[threadIdx.x] = (i < n) ? degi[i] : 0;
    __syncthreads();
    for (int off = 128; off > 0; off >>= 1) {
        if (threadIdx.x < off) s[threadIdx.x] += s[threadIdx.x + off];
        __syncthreads();
    }
    if (threadIdx.x == 0) partial[blockIdx.x] = s[0];
}

// scan_final also reduces the block-offset from raw per-block sums (scan_partials folded in)
__global__ __launch_bounds__(256) void scan_final(const int* __restrict__ degi,
                                                  const int* __restrict__ partial,
                                                  int* __restrict__ rowstart, int n, int nb)
{
    __shared__ int s[256];
    __shared__ int ps[256];
    int tid = threadIdx.x;
    ps[tid] = (tid < nb && tid < (int)blockIdx.x) ? partial[tid] : 0;
    __syncthreads();
    for (int off = 128; off > 0; off >>= 1) {
        if (tid < off) ps[tid] += ps[tid + off];
        __syncthreads();
    }
    int offset = ps[0];
    int i = blockIdx.x * 256 + tid;
    int v = (i < n) ? degi[i] : 0;
    s[tid] = v;
    __syncthreads();
    for (int off = 1; off < 256; off <<= 1) {
        int t = (tid >= off) ? s[tid - off] : 0;
        __syncthreads();
        s[tid] += t;
        __syncthreads();
    }
    if (i < n) rowstart[i] = offset + s[tid] - v;
}

__global__ void fillcsr_kernel(const int* __restrict__ src, const int* __restrict__ dst,
                               const int* __restrict__ rowstart, int* __restrict__ cursor,
                               int* __restrict__ csr, int E)
{
    int i = blockIdx.x * blockDim.x + threadIdx.x;
    if (i < E) {
        int d = dst[i];
        int p = atomicAdd(&cursor[d], 1);
        csr[rowstart[d] + p] = src[i];
    }
}

// ======== gather16_bn: 16-lane group per edge, BN_L1+ReLU applied inline on raw input ========
// in: raw X (compact 128-col rows); out: AGG (compact 128-col rows) = mean(ReLU(BN(X[src])))
__global__ __launch_bounds__(256) void gather16_bn(
    const ushort* __restrict__ X, const int* __restrict__ rowstart,
    const int* __restrict__ degi, const int* __restrict__ csr,
    ushort* __restrict__ AGG, int nN,
    const float* __restrict__ isums, const float* __restrict__ isqs,
    const float* __restrict__ igam, const float* __restrict__ ibet, float invM)
{
    int wv = (blockIdx.x * blockDim.x + threadIdx.x) >> 6;
    int lane = threadIdx.x & 63;
    if (wv >= nN) return;
    int g = lane >> 4;        // edge slot 0..3
    int sc = lane & 15;       // 16-B chunk of row
    // per-lane BN params for channels sc*8..sc*8+7
    float sc8[8], sh8[8];
    {
        int cb = sc * 8;
        #pragma unroll
        for (int e = 0; e < 8; e++) {
            float mean = isums[cb + e] * invM;
            float var = isqs[cb + e] * invM - mean * mean;
            float s = igam[cb + e] * rsqrtf(var + BN_EPS);
            sc8[e] = s;
            sh8[e] = ibet[cb + e] - mean * s;
        }
    }
    int start = rowstart[wv], d = degi[wv];
    const ushort* Xc = X + sc * 8;
    float acc[8] = {};
    auto accbn8 = [&](us8 v) {
        #pragma unroll
        for (int e = 0; e < 8; e++)
            acc[e] += fmaxf(bf2f(v[e]) * sc8[e] + sh8[e], 0.f);
    };
    if (d > 0) {
        int dm = (d < 64) ? d : 64;
        int idx_l = csr[start + ((lane < dm) ? lane : (dm - 1))];
        int j = 0;
        for (; j + 8 <= dm; j += 8) {
            int i0 = __shfl(idx_l, j + g, 64);
            int i1 = __shfl(idx_l, j + 4 + g, 64);
            us8 v0 = *(const us8*)(Xc + (long)i0 * 128);
            us8 v1 = *(const us8*)(Xc + (long)i1 * 128);
            accbn8(v0);
            accbn8(v1);
        }
        if (j + 4 <= dm) {
            int i0 = __shfl(idx_l, j + g, 64);
            us8 v0 = *(const us8*)(Xc + (long)i0 * 128);
            accbn8(v0);
            j += 4;
        }
        int rem = dm - j;
        if (rem > 0) {
            int sl = j + ((g < rem) ? g : (rem - 1));
            int i0 = __shfl(idx_l, sl, 64);
            if (g < rem) {
                us8 v0 = *(const us8*)(Xc + (long)i0 * 128);
                accbn8(v0);
            }
        }
        for (int jj = 64; jj < d; jj += 4) {     // rare: degree > 64
            if (jj + g < d) {
                int i0 = csr[start + jj + g];
                us8 v0 = *(const us8*)(Xc + (long)i0 * 128);
                accbn8(v0);
            }
        }
    }
    #pragma unroll
    for (int e = 0; e < 8; e++) {
        acc[e] += __shfl_xor(acc[e], 16, 64);
        acc[e] += __shfl_xor(acc[e], 32, 64);
    }
    if (g == 0) {
        float inv = 1.f / fmaxf((float)d, 1.f);
        us8 o;
        #pragma unroll
        for (int e = 0; e < 8; e++) o[e] = f2bf(acc[e] * inv);
        *(us8*)(AGG + (long)wv * 128 + sc * 8) = o;
    }
}

// fused gather2: out = mean(Z[src, 0:128]) + Z[dst, 128:256]  (fp32 out, 128 cols)
__device__ __forceinline__ void acc8(float acc[8], us8 v) {
    #pragma unroll
    for (int e = 0; e < 8; e++) acc[e] += bf2f(v[e]);
}

__global__ __launch_bounds__(256) void gather16_fuse(
    const ushort* __restrict__ Z, const int* __restrict__ rowstart,
    const int* __restrict__ degi, const int* __restrict__ csr,
    float* __restrict__ O, int nN)
{
    int wv = (blockIdx.x * blockDim.x + threadIdx.x) >> 6;
    int lane = threadIdx.x & 63;
    if (wv >= nN) return;
    int g = lane >> 4;
    int sc = lane & 15;
    int start = rowstart[wv], d = degi[wv];
    const ushort* Zc = Z + sc * 8;
    us8 selfv = *(const us8*)(Zc + (long)wv * 256 + 128);   // independent, issued early
    float acc[8] = {};
    if (d > 0) {
        int dm = (d < 64) ? d : 64;
        int idx_l = csr[start + ((lane < dm) ? lane : (dm - 1))];
        int j = 0;
        for (; j + 8 <= dm; j += 8) {
            int i0 = __shfl(idx_l, j + g, 64);
            int i1 = __shfl(idx_l, j + 4 + g, 64);
            us8 v0 = *(const us8*)(Zc + (long)i0 * 256);
            us8 v1 = *(const us8*)(Zc + (long)i1 * 256);
            acc8(acc, v0);
            acc8(acc, v1);
        }
        if (j + 4 <= dm) {
            int i0 = __shfl(idx_l, j + g, 64);
            us8 v0 = *(const us8*)(Zc + (long)i0 * 256);
            acc8(acc, v0);
            j += 4;
        }
        int rem = dm - j;
        if (rem > 0) {
            int sl = j + ((g < rem) ? g : (rem - 1));
            int i0 = __shfl(idx_l, sl, 64);
            if (g < rem) {
                us8 v0 = *(const us8*)(Zc + (long)i0 * 256);
                acc8(acc, v0);
            }
        }
        for (int jj = 64; jj < d; jj += 4) {
            if (jj + g < d) {
                int i0 = csr[start + jj + g];
                us8 v0 = *(const us8*)(Zc + (long)i0 * 256);
                acc8(acc, v0);
            }
        }
    }
    #pragma unroll
    for (int e = 0; e < 8; e++) {
        acc[e] += __shfl_xor(acc[e], 16, 64);
        acc[e] += __shfl_xor(acc[e], 32, 64);
    }
    if (g == 0) {
        float inv = 1.f / fmaxf((float)d, 1.f);
        float r[8];
        #pragma unroll
        for (int e = 0; e < 8; e++) r[e] = acc[e] * inv + bf2f(selfv[e]);
        float* op = O + (long)wv * 128 + sc * 8;
        *(float4*)op = make_float4(r[0], r[1], r[2], r[3]);
        *(float4*)(op + 4) = make_float4(r[4], r[5], r[6], r[7]);
    }
}

extern "C" void kernel_launch(void* const* d_in, const int* in_sizes, int n_in,
                              void* d_out, int out_size, void* d_ws, size_t ws_size,
                              hipStream_t stream)
{
    const float* nodes = (const float*)d_in[0];
    const int*   src   = (const int*)d_in[1];
    const int*   dst   = (const int*)d_in[2];
    const float* Wf1   = (const float*)d_in[3];
    const float* gf1   = (const float*)d_in[5];
    const float* bef1  = (const float*)d_in[6];
    const float* Wf2   = (const float*)d_in[7];
    const float* gf2   = (const float*)d_in[9];
    const float* bef2  = (const float*)d_in[10];
    const float* Ws1   = (const float*)d_in[11];
    const float* Wn1   = (const float*)d_in[12];
    const float* gs1   = (const float*)d_in[14];
    const float* bs1   = (const float*)d_in[15];
    const float* Ws2   = (const float*)d_in[16];
    const float* Wn2   = (const float*)d_in[17];
    const float* gs2   = (const float*)d_in[19];
    const float* bs2   = (const float*)d_in[20];
    // pre-BN biases (bf1,bf2,b1,b2) cancel under BatchNorm -> skipped

    int nN = in_sizes[0] / DIN;   // 50000
    int nE = in_sizes[1];         // 600000
    float* out = (float*)d_out;
    int mStrips = nN / 16;        // 3125 (exact)
    float invM = 1.0f / nN;

    // ---- workspace (identical layout to passing version) ----
    ushort* PRE = (ushort*)d_ws;                      // nN*256 bf16 raw GEMM out
    ushort* BF1 = PRE + (size_t)nN * 256;             // nN*256 bf16 (Xn / FF2 raw, compact 128)
    ushort* BF2 = BF1 + (size_t)nN * 256;             // nN*256 bf16 (AGG compact / Z)
    float* stats = (float*)(BF2 + (size_t)nN * 256);  // 2048 floats, 4 layer-regions
    float* scale = stats + 2048;                      // 256 (unused, kept for layout)
    float* shift = scale + 256;                       // 256 (unused, kept for layout)
    ushort* WT   = (ushort*)(shift + 256);            // 196608 shorts
    int* degi     = (int*)(WT + 196608);              // nN
    int* cursor   = degi + nN;                        // nN (adjacent: zeroed together)
    int* rowstart = cursor + nN;                      // nN
    int* partial  = rowstart + nN;                    // 256
    int* csr      = partial + 256;                    // nE

    ushort* Wf1T = WT;
    ushort* Wf2T = WT + 32768;
    ushort* Wc1T = WT + 65536;
    ushort* Wc2T = WT + 131072;
    ushort* AGG  = BF2;                               // compact nN*128 agg buffer

    dim3 blk(256);
    auto cdiv = [](int a, int b) { return (a + b - 1) / b; };
    int nScanBlocks = cdiv(nN, 256);                  // 196 (must be <= 256)

    // ---- fused setup: convert + weight transpose + zero stats/degi/cursor ----
    int nConv4 = nN * DIN / 4;
    int nbConv = cdiv(nConv4, 256);
    int nZero4 = (2 * nN) / 4;
    int nbZero = cdiv(nZero4, 256);
    setup_all<<<dim3(nbConv + 768 + nbZero + 2), blk, 0, stream>>>(
        nodes, BF1, nConv4, nbConv,
        Wf1, Wf2, Ws1, Wn1, Wn2, Ws2, WT,
        degi, nZero4, nbZero, stats);

    // ---- CSR build ----
    degcount_kernel<<<dim3(cdiv(nE, 256)), blk, 0, stream>>>(dst, degi, nE);
    scan_block_sums<<<dim3(nScanBlocks), blk, 0, stream>>>(degi, partial, nN);
    scan_final<<<dim3(nScanBlocks), blk, 0, stream>>>(degi, partial, rowstart, nN, nScanBlocks);
    fillcsr_kernel<<<dim3(cdiv(nE, 256)), blk, 0, stream>>>(src, dst, rowstart, cursor, csr, nE);

    // ---- FF1: PRE = Xn @ Wf1T (K=128, N=256, stats->L0), plain staging ----
    gemm_lds<4, 4, 0, 1, 0><<<dim3(512), blk, 0, stream>>>(
        BF1, Wf1T, PRE, mStrips, 256, stats, stats + 256,
        nullptr, nullptr, nullptr, nullptr, 0.f, 0.f, nullptr);

    // ---- FF2: BF1 = act(BN_L0(PRE)) @ Wf2T (BNIN=1; K=256, N=128 compact, stats->L1) ----
    gemm_lds<8, 2, 0, 1, 1><<<dim3(512), blk, 0, stream>>>(
        PRE, Wf2T, BF1, mStrips, 128, stats + 512, stats + 768,
        stats, stats + 256, gf1, bef1, invM, 0.0f, nullptr);

    // ---- gather1 (BN fused): AGG = mean-gather(ReLU(BN_L1(BF1))) ----
    gather16_bn<<<dim3(cdiv(nN * 64, 256)), blk, 0, stream>>>(
        BF1, rowstart, degi, csr, AGG, nN,
        stats + 512, stats + 768, gf2, bef2, invM);

    // ---- SAGE1: PRE = [ReLU(BN_L1(BF1)) | AGG] @ [Ws1;Wn1] (BNIN=2 dual-source;
    //      K=256, N=256, stats->L2) ----
    gemm_lds<8, 4, 0, 1, 2><<<dim3(512), blk, 0, stream>>>(
        BF1, Wc1T, PRE, mStrips, 256, stats + 1024, stats + 1280,
        stats + 512, stats + 768, gf2, bef2, invM, 0.0f, AGG);

    // ---- SAGE2: BF2 = act(BN_L2(PRE)) @ [Wn2|Ws2] (BNIN=1; K=256, N=256, NT=2, no stats) ----
    gemm_lds<8, 2, 1, 0, 1><<<dim3(512), blk, 0, stream>>>(
        PRE, Wc2T, BF2, mStrips, 256, nullptr, nullptr,
        stats + 1024, stats + 1280, gs1, bs1, invM, 0.01f, nullptr);

    // ---- gather_fuse -> out(fp32) ----
    gather16_fuse<<<dim3(cdiv(nN * 64, 256)), blk, 0, stream>>>(BF2, rowstart, degi, csr, out, nN);

    // ---- final: colstats -> fused BN+LReLU on out ----
    colstats128<<<dim3(120), blk, 0, stream>>>(out, stats + 1536, stats + 1792, nN);
    bnact_f32<<<dim3(2048), blk, 0, stream>>>(out, stats + 1536, stats + 1792, gs2, bs2, invM,
                                              nN, 0.01f);
}